// Round 14
// baseline (693.662 us; speedup 1.0000x reference)
//
#include <hip/hip_runtime.h>
#include <hip/hip_bf16.h>
#include <cmath>

#define T_  64
#define B_  256
#define D_  2000
#define TN_ 3000
#define E_  256
#define H_  256
#define A_  128
#define V_  128
#define PS_ 64
#define PE_ 64
#define S_  128
#define G1N_ 1500
#define G1L_ 4
#define G2N_ 1500
#define G2L_ 6
#define M_  (T_ * B_)
#define KF_ (H_ + V_ + PE_)

typedef __attribute__((ext_vector_type(8))) short short8_t;
typedef __attribute__((ext_vector_type(4))) float floatx4;
typedef _Float16 __attribute__((ext_vector_type(2))) h2_t;
typedef _Float16 __attribute__((ext_vector_type(8))) h8_t;

static __device__ __forceinline__ float sigmoidf_(float x) {
    return 1.0f / (1.0f + __expf(-x));
}

static __device__ __forceinline__ void bsplit_(float v, __hip_bfloat16& hi, __hip_bfloat16& lo) {
    hi = __float2bfloat16(v);
    lo = __float2bfloat16(v - __bfloat162float(hi));
}

static __device__ __forceinline__ float dot2_(unsigned int w, unsigned int h, float acc) {
    union { unsigned int u; h2_t h; } cw, ch;
    cw.u = w; ch.u = h;
#if __has_builtin(__builtin_amdgcn_fdot2)
    return __builtin_amdgcn_fdot2(cw.h, ch.h, acc, false);
#else
    return acc + (float)cw.h[0] * (float)ch.h[0] + (float)cw.h[1] * (float)ch.h[1];
#endif
}

// async global->LDS, 16B per lane. LDS dst must be wave-uniform base + lane*16.
static __device__ __forceinline__ void gl_lds16(const void* g, void* l)
{
#if __has_builtin(__builtin_amdgcn_global_load_lds)
    __builtin_amdgcn_global_load_lds(
        (const __attribute__((address_space(1))) void*)g,
        (__attribute__((address_space(3))) void*)l, 16, 0, 0);
#else
    *(short8_t*)l = *(const short8_t*)g;
#endif
}

template<int DT>
static __device__ __forceinline__ floatx4 mfma16_(short8_t a, short8_t b, floatx4 c) {
    if constexpr (DT == 0) {
        return __builtin_amdgcn_mfma_f32_16x16x32_bf16(a, b, c, 0, 0, 0);
    } else {
        union { short8_t s; h8_t h; } ua, ub;
        ua.s = a; ub.s = b;
        return __builtin_amdgcn_mfma_f32_16x16x32_f16(ua.h, ub.h, c, 0, 0, 0);
    }
}

// ---------------------------------------------------------------------------
// Split MFMA GEMM, double-buffered global_load_lds staging + XCD remap.
// DT=0: bf16 planes (NPH=3 -> fp32-grade). DT=1: f16, NPH=1 (hi-only).
// B given as BT[Npad][K] row-major. M mult 128, K mult 32, Npad = nblk*128.
// EPI 1: sigmoid col<128 else tanh. EPI 2: sigmoid col<128, tanh col<256.
// OUTMODE 0: f32 Cf (ACCUM adds). 1: bf16 split (Chi,Clo). 2: f16 (Chi cast).
// ---------------------------------------------------------------------------
template<int EPI, bool ACCUM, int OUTMODE, int NPH, int DT>
__global__ __launch_bounds__(256)
void k_mgemm3(const __hip_bfloat16* __restrict__ Ahi, const __hip_bfloat16* __restrict__ Alo,
              const __hip_bfloat16* __restrict__ Bhi, const __hip_bfloat16* __restrict__ Blo,
              const float* __restrict__ bias, float* __restrict__ Cf,
              __hip_bfloat16* __restrict__ Chi, __hip_bfloat16* __restrict__ Clo,
              int K, int Nreal, int nblk)
{
    __shared__ __align__(16) short As[2][4096];
    __shared__ __align__(16) short Bs[2][4096];

    const int tid  = threadIdx.x;
    const int lane = tid & 63;
    const int w    = tid >> 6;
    const int wm   = w >> 1, wn = w & 1;
    const int lr   = lane & 15;
    const int lkc  = lane >> 4;

    const int bx = blockIdx.x;
    const int xcd = bx & 7, loc = bx >> 3;
    const int mchunk = (int)gridDim.x / (8 * nblk);
    const int m0 = (xcd * mchunk + loc / nblk) * 128;
    const int n0 = (loc % nblk) * 128;

    const int fa = 2 * w;
    const size_t aoff0 = (size_t)(m0 + fa * 16 + lr) * K + lkc * 8;
    const size_t aoff1 = aoff0 + (size_t)16 * K;
    const size_t boff0 = (size_t)(n0 + fa * 16 + lr) * K + lkc * 8;
    const size_t boff1 = boff0 + (size_t)16 * K;

    const int lA0 = (fa    ) * 512 + lane * 8;
    const int lA1 = (fa + 1) * 512 + lane * 8;

    floatx4 acc[4][4];
#pragma unroll
    for (int i = 0; i < 4; ++i)
#pragma unroll
        for (int j = 0; j < 4; ++j) acc[i][j] = floatx4{0.f, 0.f, 0.f, 0.f};

    const int KT = K >> 5;
    const int NT = NPH * KT;

    int s_ph = 0, s_k = 0;
    auto do_stage = [&](int buf) {
        const __hip_bfloat16* Ap = (s_ph == 2) ? Alo : Ahi;
        const __hip_bfloat16* Bp = (s_ph == 1) ? Blo : Bhi;
        gl_lds16(Ap + aoff0 + s_k, &As[buf][lA0]);
        gl_lds16(Ap + aoff1 + s_k, &As[buf][lA1]);
        gl_lds16(Bp + boff0 + s_k, &Bs[buf][lA0]);
        gl_lds16(Bp + boff1 + s_k, &Bs[buf][lA1]);
        s_k += 32;
        if (s_k >= K) { s_k = 0; ++s_ph; }
    };

    do_stage(0);
    __syncthreads();

#pragma unroll 1
    for (int t = 0; t < NT; ++t) {
        const int cur = t & 1;
        if (t + 1 < NT) do_stage(cur ^ 1);

        short8_t af[4], bf[4];
#pragma unroll
        for (int i = 0; i < 4; ++i)
            af[i] = *(const short8_t*)(const void*)&As[cur][(wm * 4 + i) * 512 + lane * 8];
#pragma unroll
        for (int j = 0; j < 4; ++j)
            bf[j] = *(const short8_t*)(const void*)&Bs[cur][(wn * 4 + j) * 512 + lane * 8];
#pragma unroll
        for (int i = 0; i < 4; ++i)
#pragma unroll
            for (int j = 0; j < 4; ++j)
                acc[i][j] = mfma16_<DT>(af[i], bf[j], acc[i][j]);

        __syncthreads();
    }

    // C/D layout (m89-verified): col=lane&15, row=(lane>>4)*4+r
#pragma unroll
    for (int i = 0; i < 4; ++i) {
        const int row = m0 + wm * 64 + i * 16 + (lane >> 4) * 4;
#pragma unroll
        for (int j = 0; j < 4; ++j) {
            const int col = n0 + wn * 64 + j * 16 + (lane & 15);
            if (col < Nreal) {
                float bv = bias ? bias[col] : 0.0f;
#pragma unroll
                for (int r = 0; r < 4; ++r) {
                    float v = acc[i][j][r] + bv;
                    if (EPI == 1) v = (col < 128) ? sigmoidf_(v) : tanhf(v);
                    if (EPI == 2) {
                        if (col < 128) v = sigmoidf_(v);
                        else if (col < 256) v = tanhf(v);
                    }
                    size_t o = (size_t)(row + r) * Nreal + col;
                    if (OUTMODE == 0) {
                        if (ACCUM) v += Cf[o];
                        Cf[o] = v;
                    } else if (OUTMODE == 1) {
                        __hip_bfloat16 h, l;
                        bsplit_(v, h, l);
                        Chi[o] = h; Clo[o] = l;
                    } else {
                        ((_Float16*)Chi)[o] = (_Float16)v;
                    }
                }
            }
        }
    }
}

// ---------------------------------------------------------------------------
// X f32 [16384][2000] -> XH f16 [16384][2048] (pad cols zero), vectorized
// ---------------------------------------------------------------------------
__global__ __launch_bounds__(256)
void k_cvtX(const float* __restrict__ X, _Float16* __restrict__ XH)
{
    int idx = blockIdx.x * blockDim.x + threadIdx.x;
    if (idx >= M_ * 256) return;
    int m = idx >> 8, d0 = (idx & 255) * 8;
    _Float16 h[8];
    if (d0 + 7 < D_) {
        float4 p = *(const float4*)(X + (size_t)m * D_ + d0);
        float4 q = *(const float4*)(X + (size_t)m * D_ + d0 + 4);
        h[0]=(_Float16)p.x; h[1]=(_Float16)p.y; h[2]=(_Float16)p.z; h[3]=(_Float16)p.w;
        h[4]=(_Float16)q.x; h[5]=(_Float16)q.y; h[6]=(_Float16)q.z; h[7]=(_Float16)q.w;
    } else {
#pragma unroll
        for (int i = 0; i < 8; ++i)
            h[i] = (d0 + i < D_) ? (_Float16)X[(size_t)m * D_ + d0 + i] : (_Float16)0.0f;
    }
    *(short8_t*)(XH + (size_t)m * 2048 + d0) = *(short8_t*)h;
}

// ---------------------------------------------------------------------------
// Xe GEMM: A = XH f16 [16384][2048], B = EMB f16 hi/lo planes [256][2048].
// Double-buffered DMA staging; XCD remap. Writes Xe bf16 split planes.
// ---------------------------------------------------------------------------
__global__ __launch_bounds__(256)
void k_mgemmXh(const _Float16* __restrict__ XH,
               const _Float16* __restrict__ Bhi, const _Float16* __restrict__ Blo,
               __hip_bfloat16* __restrict__ Chi, __hip_bfloat16* __restrict__ Clo)
{
    const int KP = 2048, NN = 256, nblk = 2;
    __shared__ __align__(16) short Ah[2][4096];
    __shared__ __align__(16) short Bh[2][4096];
    __shared__ __align__(16) short Bl[2][4096];

    const int tid  = threadIdx.x;
    const int lane = tid & 63;
    const int w    = tid >> 6;
    const int wm   = w >> 1, wn = w & 1;
    const int lr   = lane & 15;
    const int lkc  = lane >> 4;

    const int bx = blockIdx.x;
    const int xcd = bx & 7, loc = bx >> 3;
    const int mchunk = 256 / (8 * nblk);
    const int m0 = (xcd * mchunk + loc / nblk) * 128;
    const int n0 = (loc % nblk) * 128;

    const int fa = 2 * w;
    const size_t aoff0 = (size_t)(m0 + fa * 16 + lr) * KP + lkc * 8;
    const size_t aoff1 = aoff0 + (size_t)16 * KP;
    const size_t boff0 = (size_t)(n0 + fa * 16 + lr) * KP + lkc * 8;
    const size_t boff1 = boff0 + (size_t)16 * KP;

    const int lA0 = (fa    ) * 512 + lane * 8;
    const int lA1 = (fa + 1) * 512 + lane * 8;

    floatx4 acc[4][4];
#pragma unroll
    for (int i = 0; i < 4; ++i)
#pragma unroll
        for (int j = 0; j < 4; ++j) acc[i][j] = floatx4{0.f, 0.f, 0.f, 0.f};

    int s_k = 0;
    auto do_stage = [&](int buf) {
        gl_lds16(XH  + aoff0 + s_k, &Ah[buf][lA0]);
        gl_lds16(XH  + aoff1 + s_k, &Ah[buf][lA1]);
        gl_lds16(Bhi + boff0 + s_k, &Bh[buf][lA0]);
        gl_lds16(Bhi + boff1 + s_k, &Bh[buf][lA1]);
        gl_lds16(Blo + boff0 + s_k, &Bl[buf][lA0]);
        gl_lds16(Blo + boff1 + s_k, &Bl[buf][lA1]);
        s_k += 32;
    };

    do_stage(0);
    __syncthreads();

#pragma unroll 1
    for (int t = 0; t < KP / 32; ++t) {
        const int cur = t & 1;
        if (s_k < KP) do_stage(cur ^ 1);

        short8_t af[4], bfh[4], bfl[4];
#pragma unroll
        for (int i = 0; i < 4; ++i) {
            af[i]  = *(const short8_t*)(const void*)&Ah[cur][(wm * 4 + i) * 512 + lane * 8];
            bfh[i] = *(const short8_t*)(const void*)&Bh[cur][(wn * 4 + i) * 512 + lane * 8];
        }
#pragma unroll
        for (int i = 0; i < 4; ++i)
#pragma unroll
            for (int j = 0; j < 4; ++j)
                acc[i][j] = mfma16_<1>(af[i], bfh[j], acc[i][j]);
#pragma unroll
        for (int j = 0; j < 4; ++j)
            bfl[j] = *(const short8_t*)(const void*)&Bl[cur][(wn * 4 + j) * 512 + lane * 8];
#pragma unroll
        for (int i = 0; i < 4; ++i)
#pragma unroll
            for (int j = 0; j < 4; ++j)
                acc[i][j] = mfma16_<1>(af[i], bfl[j], acc[i][j]);

        __syncthreads();
    }

#pragma unroll
    for (int i = 0; i < 4; ++i) {
        const int row = m0 + wm * 64 + i * 16 + (lane >> 4) * 4;
#pragma unroll
        for (int j = 0; j < 4; ++j) {
            const int col = n0 + wn * 64 + j * 16 + (lane & 15);
#pragma unroll
            for (int r = 0; r < 4; ++r) {
                float v = acc[i][j][r];
                size_t o = (size_t)(row + r) * NN + col;
                __hip_bfloat16 h, l;
                bsplit_(v, h, l);
                Chi[o] = h; Clo[o] = l;
            }
        }
    }
}

// ---------------------------------------------------------------------------
// fp32 tiled GEMM (PP = ini_embd @ W2 only)
// ---------------------------------------------------------------------------
template<int BM, int BN, int BK, int TM, int TN>
__global__ __launch_bounds__(256)
void k_gemm(const float* __restrict__ A, const float* __restrict__ B,
            float* __restrict__ C, int M, int N, int K)
{
    __shared__ float As[BK][BM + 4];
    __shared__ float Bs[BK][BN + 4];
    const int tid = threadIdx.y * blockDim.x + threadIdx.x;
    const int m0 = blockIdx.y * BM;
    const int n0 = blockIdx.x * BN;
    float acc[TM][TN];
#pragma unroll
    for (int i = 0; i < TM; ++i)
#pragma unroll
        for (int j = 0; j < TN; ++j) acc[i][j] = 0.0f;
    for (int k0 = 0; k0 < K; k0 += BK) {
#pragma unroll
        for (int i = tid; i < BM * BK; i += 256) {
            int r = i / BK, c = i % BK;
            int m = m0 + r;
            As[c][r] = (m < M) ? A[(size_t)m * K + k0 + c] : 0.0f;
        }
#pragma unroll
        for (int i = tid; i < BK * BN; i += 256) {
            int r = i / BN, c = i % BN;
            Bs[r][c] = B[(size_t)(k0 + r) * N + n0 + c];
        }
        __syncthreads();
#pragma unroll
        for (int kk = 0; kk < BK; ++kk) {
            float a[TM], b[TN];
#pragma unroll
            for (int i = 0; i < TM; ++i) a[i] = As[kk][threadIdx.y * TM + i];
#pragma unroll
            for (int j = 0; j < TN; ++j) b[j] = Bs[kk][threadIdx.x * TN + j];
#pragma unroll
            for (int i = 0; i < TM; ++i)
#pragma unroll
                for (int j = 0; j < TN; ++j) acc[i][j] += a[i] * b[j];
        }
        __syncthreads();
    }
#pragma unroll
    for (int i = 0; i < TM; ++i) {
        int m = m0 + threadIdx.y * TM + i;
        if (m >= M) continue;
#pragma unroll
        for (int j = 0; j < TN; ++j)
            C[(size_t)m * N + n0 + threadIdx.x * TN + j] = acc[i][j];
    }
}

// ---------------------------------------------------------------------------
// Merged weight-pack kernel (segment-partitioned flat index).
// S0 W2p[65536] | S1 WG split[262144] | S2 biasG[1024] | S3 tranHT[81920]
// S4 outWT f16[917504] | S5 KM split[32768] | S6 W4 uint4-pack[98304]
// ---------------------------------------------------------------------------
__global__ __launch_bounds__(256)
void k_packall(const float* __restrict__ Wa_w,
               const float* __restrict__ erase_w, const float* __restrict__ add_w,
               const float* __restrict__ Wih,
               const float* __restrict__ erase_b, const float* __restrict__ add_b,
               const float* __restrict__ bih,
               const float* __restrict__ tranH_w, const float* __restrict__ out_w,
               const float* __restrict__ ini_embd, const int* __restrict__ KMIds,
               const float* __restrict__ Whh,
               float* __restrict__ W2p,
               __hip_bfloat16* __restrict__ WGhi, __hip_bfloat16* __restrict__ WGlo,
               float* __restrict__ biasG,
               __hip_bfloat16* __restrict__ THhi, __hip_bfloat16* __restrict__ THlo,
               _Float16* __restrict__ OWf,
               __hip_bfloat16* __restrict__ KMhi, __hip_bfloat16* __restrict__ KMlo,
               unsigned int* __restrict__ W4)
{
    int idx = blockIdx.x * blockDim.x + threadIdx.x;
    if (idx < 65536) {
        int e = idx >> 8, j = idx & 255;
        W2p[idx] = (j < A_) ? Wa_w[(size_t)e * A_ + j]
                            : Wa_w[(size_t)(E_ + e) * A_ + (j - A_)];
        return;
    }
    idx -= 65536;
    if (idx < 262144) {
        int n = idx >> 8, k = idx & 255;
        float v;
        if (n < 128)      v = erase_w[(size_t)k * V_ + n];
        else if (n < 256) v = add_w[(size_t)k * V_ + (n - 128)];
        else              v = Wih[(size_t)(n - 256) * 256 + k];
        bsplit_(v, WGhi[idx], WGlo[idx]);
        return;
    }
    idx -= 262144;
    if (idx < 1024) {
        biasG[idx] = (idx < 128) ? erase_b[idx]
                   : (idx < 256) ? add_b[idx - 128]
                                 : bih[idx - 256];
        return;
    }
    idx -= 1024;
    if (idx < 81920) {
        int n = idx / 320, k = idx % 320;
        bsplit_(tranH_w[(size_t)k * 256 + n], THhi[idx], THlo[idx]);
        return;
    }
    idx -= 81920;
    if (idx < 917504) {
        int n = idx / 448, k = idx % 448;
        OWf[idx] = (n < D_) ? (_Float16)out_w[(size_t)k * D_ + n] : (_Float16)0.0f;
        return;
    }
    idx -= 917504;
    if (idx < 32768) {
        int s = idx >> 8, k = idx & 255;
        bsplit_(ini_embd[(size_t)KMIds[s] * E_ + k], KMhi[idx], KMlo[idx]);
        return;
    }
    idx -= 32768;
    if (idx < 98304) {                                   // W4[32][768][4]
        int j = idx / 128, e2 = idx % 128;
        union { unsigned int u; h2_t h; } c;
        c.h[0] = (_Float16)Whh[(size_t)j * 256 + 2 * e2];
        c.h[1] = (_Float16)Whh[(size_t)j * 256 + 2 * e2 + 1];
        int ch = e2 >> 2, i = e2 & 3;
        W4[((size_t)ch * 768 + j) * 4 + i] = c.u;
    }
}

__global__ void k_prof(const float* __restrict__ profiles, const float* __restrict__ emP_w,
                       const float* __restrict__ emP_b, float* __restrict__ prof)
{
    int b = blockIdx.x, j = threadIdx.x;
    float acc = emP_b[j];
    for (int k = 0; k < PS_; ++k) acc += profiles[(size_t)b * PS_ + k] * emP_w[(size_t)k * PE_ + j];
    prof[(size_t)b * PE_ + j] = acc;
}

// embMT full: dst[e][d] = f16 split of embG[mapInfo[d]][e], d<2000 else 0
__global__ void k_embMT_f16(const float* __restrict__ embG, const int* __restrict__ mapInfo,
                            _Float16* __restrict__ hi, _Float16* __restrict__ lo)
{
    int idx = blockIdx.x * blockDim.x + threadIdx.x;
    if (idx >= 256 * 2048) return;
    int e = idx >> 11, d = idx & 2047;
    float v = (d < D_) ? embG[(size_t)mapInfo[d] * E_ + e] : 0.0f;
    _Float16 h = (_Float16)v;
    hi[idx] = h;
    lo[idx] = (_Float16)(v - (float)h);
}

// ---------------------------------------------------------------------------
// GRAM group attention
// ---------------------------------------------------------------------------
__global__ void k_group_embed(const float* __restrict__ PP, const float* __restrict__ Wa_b,
                              const float* __restrict__ Ua_w, const float* __restrict__ ini_embd,
                              const int* __restrict__ leaves1, const int* __restrict__ anc1,
                              const int* __restrict__ leaves2, const int* __restrict__ anc2,
                              float* __restrict__ embedG)
{
    int n = blockIdx.x;
    int lane = threadIdx.x;
    const int* lv; const int* ac; int L;
    if (n < G1N_) { L = G1L_; lv = leaves1 + (size_t)n * G1L_; ac = anc1 + (size_t)n * G1L_; }
    else { int n2 = n - G1N_; L = G2L_; lv = leaves2 + (size_t)n2 * G2L_; ac = anc2 + (size_t)n2 * G2L_; }

    float score[6]; int ai[6];
    for (int l = 0; l < L; ++l) {
        int li = lv[l]; int av = ac[l]; ai[l] = av;
        float s = 0.0f;
        for (int a = lane; a < A_; a += 64) {
            float hv = tanhf(PP[(size_t)li * 256 + a] + PP[(size_t)av * 256 + 128 + a] + Wa_b[a]);
            s += hv * Ua_w[a];
        }
        for (int o = 32; o; o >>= 1) s += __shfl_xor(s, o);
        score[l] = s;
    }
    float mx = -1e30f;
    for (int l = 0; l < L; ++l) mx = fmaxf(mx, score[l]);
    float w[6], sum = 0.0f;
    for (int l = 0; l < L; ++l) { w[l] = __expf(score[l] - mx); sum += w[l]; }
    float inv = 1.0f / sum;
    for (int e = lane; e < E_; e += 64) {
        float acc = 0.0f;
        for (int l = 0; l < L; ++l) acc += w[l] * inv * ini_embd[(size_t)ai[l] * E_ + e];
        embedG[(size_t)n * E_ + e] = acc;
    }
}

// ---------------------------------------------------------------------------
// GRU scan v7: 256 wgs x 768 threads, 1 sample/wg.
// Weights streamed as uint4 [32][768][4], explicit 8-deep double buffer
// (wa/wb), fully unrolled. h written directly to F16 cols 0..255 (f16) and
// At planes; prof section of At written by threads 256..319.
// ---------------------------------------------------------------------------
__global__ __launch_bounds__(768)
void k_gru7(const float* __restrict__ Cg, const uint4* __restrict__ W4,
            const float* __restrict__ bhh, const int* __restrict__ X_len,
            const float* __restrict__ prof, _Float16* __restrict__ F,
            __hip_bfloat16* __restrict__ At_hi, __hip_bfloat16* __restrict__ At_lo)
{
    const int b = blockIdx.x;
    const int tid = threadIdx.x;

    __shared__ uint4 h2S[32];
    __shared__ float ghS[768];
    __shared__ float gxnS[256];

    if (tid < 128) ((unsigned int*)h2S)[tid] = 0u;

    float hreg = 0.0f;
    const int len = X_len[b];
    const float bj = bhh[tid];

    __hip_bfloat16 phi, plo;
    if (tid >= 256 && tid < 320)
        bsplit_(prof[(size_t)b * PE_ + (tid - 256)], phi, plo);

    __syncthreads();

#define DOT8(BUF, BASE)                                                     \
    {                                                                       \
        _Pragma("unroll")                                                   \
        for (int s = 0; s < 8; ++s) {                                       \
            uint4 h = h2S[(BASE) + s];                                      \
            a0 = dot2_(BUF[s].x, h.x, a0);                                  \
            a0 = dot2_(BUF[s].y, h.y, a0);                                  \
            a0 = dot2_(BUF[s].z, h.z, a0);                                  \
            a0 = dot2_(BUF[s].w, h.w, a0);                                  \
        }                                                                   \
    }
#define LOAD8(BUF, BASE)                                                    \
    {                                                                       \
        _Pragma("unroll")                                                   \
        for (int s = 0; s < 8; ++s)                                         \
            BUF[s] = W4[(size_t)((BASE) + s) * 768 + tid];                  \
    }

    for (int t = 0; t < T_; ++t) {
        float gxv = Cg[((size_t)t * B_ + b) * 1024 + 256 + tid];

        uint4 wa[8], wb[8];
        LOAD8(wa, 0)
        float a0 = bj;
        LOAD8(wb, 8)
        DOT8(wa, 0)
        LOAD8(wa, 16)
        DOT8(wb, 8)
        LOAD8(wb, 24)
        DOT8(wa, 16)
        DOT8(wb, 24)

        if (tid < 512) ghS[tid] = a0 + gxv;
        else { ghS[tid] = a0; gxnS[tid - 512] = gxv; }
        __syncthreads();

        if (tid < 256) {
            float r  = sigmoidf_(ghS[tid]);
            float z  = sigmoidf_(ghS[256 + tid]);
            float nn = tanhf(gxnS[tid] + r * ghS[512 + tid]);
            float hnew = (1.0f - z) * nn + z * hreg;
            bool msk = (t < len);
            hreg = msk ? hnew : hreg;
            float ov = msk ? hreg : 0.0f;
            size_t m = (size_t)t * B_ + b;
            F[m * KF_ + tid] = (_Float16)ov;
            size_t o = m * 320 + tid;
            bsplit_(ov, At_hi[o], At_lo[o]);
            float partner = __shfl_xor(hreg, 1);
            if (!(tid & 1)) {
                union { unsigned int u; h2_t h; } p;
                p.h[0] = (_Float16)hreg;
                p.h[1] = (_Float16)partner;
                ((unsigned int*)h2S)[tid >> 1] = p.u;
            }
        } else if (tid < 320) {
            size_t o = ((size_t)t * B_ + b) * 320 + tid;
            At_hi[o] = phi;
            At_lo[o] = plo;
        }
        __syncthreads();
    }
#undef DOT8
#undef LOAD8
}

// ---------------------------------------------------------------------------
// Fused: slot softmax (bit-identical to old k_softmax128) + VM scan +
// attn epilogue. Writes F16 cols 256..383 (read) and 384..447 (prof2).
// grid = B_, block = 256. LDS ~52 KB.
// ---------------------------------------------------------------------------
__global__ __launch_bounds__(256)
void k_memf(const float* __restrict__ slotw, const float* __restrict__ Cg,
            const float* __restrict__ iniVam, const float* __restrict__ prof,
            const float* __restrict__ attnP_w, const float* __restrict__ attnP_b,
            _Float16* __restrict__ F)
{
    const int b = blockIdx.x;
    const int tid = threadIdx.x;
    const int v = tid & (V_ - 1);
    const int sh = tid >> 7;
    const int sbase = sh * 64;

    __shared__ float aW[(PE_ + V_) * PE_];   // 49152 B
    __shared__ float swL[S_];
    __shared__ float eaL[2 * V_];
    __shared__ float part[V_];
    __shared__ float rdL[V_];
    __shared__ float pfL[PE_];
    __shared__ float abL[PE_];
    __shared__ float pp[4][PE_];

    for (int i = tid; i < (PE_ + V_) * PE_; i += 256) aW[i] = attnP_w[i];
    if (tid < PE_) {
        pfL[tid] = prof[(size_t)b * PE_ + tid];
        abL[tid] = attnP_b[tid];
    }

    float VM[64];
#pragma unroll
    for (int i = 0; i < 64; ++i) VM[i] = iniVam[(size_t)(sbase + i) * V_ + v];
    __syncthreads();

    for (int t = 0; t < T_; ++t) {
        size_t m = (size_t)t * B_ + b;
        if (tid < S_) swL[tid] = slotw[m * S_ + tid];
        eaL[tid] = Cg[m * 1024 + tid];
        __syncthreads();

        // softmax over 128 slot logits (wave 0; identical to old k_softmax128)
        if (tid < 64) {
            float a = swL[tid], bb = swL[64 + tid];
            float mx = fmaxf(a, bb);
            for (int o = 32; o; o >>= 1) mx = fmaxf(mx, __shfl_xor(mx, o));
            float e0 = __expf(a - mx), e1 = __expf(bb - mx);
            float s = e0 + e1;
            for (int o = 32; o; o >>= 1) s += __shfl_xor(s, o);
            float inv = 1.0f / s;
            swL[tid] = e0 * inv;
            swL[64 + tid] = e1 * inv;
        }
        __syncthreads();

        float er = eaL[v], ad = eaL[V_ + v];
        float p0 = 0.0f, p1 = 0.0f, p2 = 0.0f, p3 = 0.0f;
#pragma unroll
        for (int i = 0; i < 16; ++i) {
            float s0 = swL[sbase + 4 * i];
            float s1 = swL[sbase + 4 * i + 1];
            float s2 = swL[sbase + 4 * i + 2];
            float s3 = swL[sbase + 4 * i + 3];
            float v0 = VM[4 * i], v1 = VM[4 * i + 1], v2 = VM[4 * i + 2], v3 = VM[4 * i + 3];
            p0 += s0 * v0; p1 += s1 * v1; p2 += s2 * v2; p3 += s3 * v3;
            VM[4 * i]     = v0 * (1.0f - s0 * er) + s0 * ad;
            VM[4 * i + 1] = v1 * (1.0f - s1 * er) + s1 * ad;
            VM[4 * i + 2] = v2 * (1.0f - s2 * er) + s2 * ad;
            VM[4 * i + 3] = v3 * (1.0f - s3 * er) + s3 * ad;
        }
        float acc = (p0 + p1) + (p2 + p3);
        if (sh == 1) part[v] = acc;
        __syncthreads();
        if (sh == 0) {
            float rv = acc + part[v];
            rdL[v] = rv;
            F[m * KF_ + H_ + v] = (_Float16)rv;
        }
        __syncthreads();

        // attn: pe = tid&63, quarter q covers k in [q*48, q*48+48)
        {
            const int pe = tid & 63, q = tid >> 6;
            float s = 0.0f;
            const int k0 = q * 48;
#pragma unroll
            for (int k = 0; k < 48; ++k) {
                int kk = k0 + k;
                float xv = (kk < PE_) ? pfL[kk] : rdL[kk - PE_];
                s += xv * aW[kk * PE_ + pe];
            }
            pp[q][pe] = s;
        }
        __syncthreads();
        if (tid < PE_) {
            float a = abL[tid] + ((pp[0][tid] + pp[1][tid]) + (pp[2][tid] + pp[3][tid]));
            a = fmaxf(a, 0.0f);
            F[m * KF_ + H_ + V_ + tid] = (_Float16)(pfL[tid] * a);
        }
        __syncthreads();
    }
}

// reads f16 logits, writes f32 probabilities to d_out
__global__ __launch_bounds__(256)
void k_softmax2000(const _Float16* __restrict__ L, float* __restrict__ C)
{
    const int m = blockIdx.x;
    const size_t base = (size_t)m * D_;
    const int tid = threadIdx.x;
    const int wid = tid >> 6, lane = tid & 63;
    __shared__ float red[4], red2[4];

    float v[8];
#pragma unroll
    for (int i = 0; i < 8; ++i) {
        int d = i * 256 + tid;
        v[i] = (d < D_) ? (float)L[base + d] : -1e30f;
    }
    float mx = v[0];
#pragma unroll
    for (int i = 1; i < 8; ++i) mx = fmaxf(mx, v[i]);
    for (int o = 32; o; o >>= 1) mx = fmaxf(mx, __shfl_xor(mx, o));
    if (lane == 0) red[wid] = mx;
    __syncthreads();
    mx = fmaxf(fmaxf(red[0], red[1]), fmaxf(red[2], red[3]));

    float sum = 0.0f;
#pragma unroll
    for (int i = 0; i < 8; ++i) { v[i] = __expf(v[i] - mx); sum += v[i]; }
    for (int o = 32; o; o >>= 1) sum += __shfl_xor(sum, o);
    if (lane == 0) red2[wid] = sum;
    __syncthreads();
    sum = red2[0] + red2[1] + red2[2] + red2[3];
    float inv = 1.0f / sum;
#pragma unroll
    for (int i = 0; i < 8; ++i) {
        int d = i * 256 + tid;
        if (d < D_) C[base + d] = v[i] * inv;
    }
}

// ---------------------------------------------------------------------------
// Launch
// ---------------------------------------------------------------------------
extern "C" void kernel_launch(void* const* d_in, const int* in_sizes, int n_in,
                              void* d_out, int out_size, void* d_ws, size_t ws_size,
                              hipStream_t stream)
{
    const float* X        = (const float*)d_in[0];
    const float* profiles = (const float*)d_in[1];
    const float* ini_embd = (const float*)d_in[2];
    const float* Wa_w     = (const float*)d_in[3];
    const float* Wa_b     = (const float*)d_in[4];
    const float* Ua_w     = (const float*)d_in[5];
    const float* gru_Wih  = (const float*)d_in[6];
    const float* gru_Whh  = (const float*)d_in[7];
    const float* gru_bih  = (const float*)d_in[8];
    const float* gru_bhh  = (const float*)d_in[9];
    const float* tranH_w  = (const float*)d_in[10];
    const float* tranH_b  = (const float*)d_in[11];
    const float* out_w    = (const float*)d_in[12];
    const float* out_b    = (const float*)d_in[13];
    const float* erase_w  = (const float*)d_in[14];
    const float* erase_b  = (const float*)d_in[15];
    const float* add_w    = (const float*)d_in[16];
    const float* add_b    = (const float*)d_in[17];
    const float* iniVam   = (const float*)d_in[18];
    const float* emP_w    = (const float*)d_in[19];
    const float* emP_b    = (const float*)d_in[20];
    const float* attnP_w  = (const float*)d_in[21];
    const float* attnP_b  = (const float*)d_in[22];
    const int* KMIds   = (const int*)d_in[23];
    const int* leaves1 = (const int*)d_in[24];
    const int* anc1    = (const int*)d_in[25];
    const int* leaves2 = (const int*)d_in[26];
    const int* anc2    = (const int*)d_in[27];
    const int* mapInfo = (const int*)d_in[28];
    const int* X_len   = (const int*)d_in[29];

    char* ws = (char*)d_ws;
    float* out = (float*)d_out;
    typedef __hip_bfloat16 bf16;

    // ---- workspace layout (bytes) ----
    // R0 (67,108,864): early PP+embG; then XH f16; then Cg f32 (dead after
    //   k_memf); finally LG16 f16 logits [16384][2000] (65.5 MB).
    // R1 (16,777,216): F16 [16384][448] f16 (14.68 MB) — gru cols 0..255,
    //   memf cols 256..447; read by out-GEMM.
    // R2 (16,777,216): Xe planes; later tran planes.
    // R3 (20,971,520): At planes; later slotw.
    const size_t R0 = 0;
    const size_t R1 = 67108864;
    const size_t R2 = 83886080;
    const size_t R3 = 100663296;
    size_t P = 121634816;
    const size_t EMBHI = P; P += 1048576;
    const size_t EMBLO = P; P += 1048576;
    const size_t OWF  = P; P += 1835008;
    const size_t WGHI = P; P += 524288;
    const size_t WGLO = P; P += 524288;
    const size_t THHI = P; P += 163840;
    const size_t THLO = P; P += 163840;
    const size_t KMHI = P; P += 65536;
    const size_t KMLO = P; P += 65536;
    const size_t W4O  = P; P += 393216;   // Whh f16 uint4-pack [32][768][4]
    const size_t PROF = P; P += 65536;
    const size_t BIAS = P; P += 4096;
    const size_t W2O  = P; P += 262144;

    float* PP      = (float*)(ws + R0);
    float* embG    = (float*)(ws + R0 + 12288000);
    _Float16* XH   = (_Float16*)(ws + R0);
    float* Cg      = (float*)(ws + R0);
    _Float16* LG16 = (_Float16*)(ws + R0);
    _Float16* F16  = (_Float16*)(ws + R1);
    bf16*  Xe_hi   = (bf16*)(ws + R2);
    bf16*  Xe_lo   = (bf16*)(ws + R2 + 8388608);
    bf16*  tran_hi = (bf16*)(ws + R2);
    bf16*  tran_lo = (bf16*)(ws + R2 + 8388608);
    bf16*  At_hi   = (bf16*)(ws + R3);
    bf16*  At_lo   = (bf16*)(ws + R3 + 10485760);
    float* slotw   = (float*)(ws + R3);
    _Float16* EMBhi = (_Float16*)(ws + EMBHI);
    _Float16* EMBlo = (_Float16*)(ws + EMBLO);
    _Float16* OWf = (_Float16*)(ws + OWF);
    bf16*  WGhi = (bf16*)(ws + WGHI); bf16* WGlo = (bf16*)(ws + WGLO);
    bf16*  THhi = (bf16*)(ws + THHI); bf16* THlo = (bf16*)(ws + THLO);
    bf16*  KMhi = (bf16*)(ws + KMHI); bf16* KMlo = (bf16*)(ws + KMLO);
    unsigned int* W4 = (unsigned int*)(ws + W4O);
    float* prof  = (float*)(ws + PROF);
    float* biasG = (float*)(ws + BIAS);
    float* W2p   = (float*)(ws + W2O);

    // ---- merged weight packs ----
    k_packall<<<5700, 256, 0, stream>>>(Wa_w, erase_w, add_w, gru_Wih,
        erase_b, add_b, gru_bih, tranH_w, out_w, ini_embd, KMIds, gru_Whh,
        W2p, WGhi, WGlo, biasG, THhi, THlo, OWf, KMhi, KMlo, W4);
    k_prof<<<B_, PE_, 0, stream>>>(profiles, emP_w, emP_b, prof);

    // ---- ontology attention -> embedMat f16 planes ----
    {
        dim3 blk(16, 16);
        dim3 grid(4, (TN_ + 63) / 64);
        k_gemm<64, 64, 16, 4, 4><<<grid, blk, 0, stream>>>(ini_embd, W2p, PP, TN_, 256, E_);
    }
    k_group_embed<<<G1N_ + G2N_, 64, 0, stream>>>(PP, Wa_b, Ua_w, ini_embd,
                                                  leaves1, anc1, leaves2, anc2, embG);
    k_embMT_f16<<<(256 * 2048) / 256, 256, 0, stream>>>(embG, mapInfo, EMBhi, EMBlo);

    // ---- X -> f16 (overwrites PP/embG region; both dead) ----
    k_cvtX<<<(M_ * 256) / 256, 256, 0, stream>>>(X, XH);

    // ---- Xe = XH @ embM (double-buffered DMA, f16 2-phase) ----
    k_mgemmXh<<<128 * 2, 256, 0, stream>>>(XH, EMBhi, EMBlo, Xe_hi, Xe_lo);

    // ---- Cg = [era | gx] fused GEMM (bf16 3-phase, fp32-grade) ----
    k_mgemm3<2, false, 0, 3, 0><<<128 * 8, 256, 0, stream>>>(Xe_hi, Xe_lo, WGhi, WGlo,
        biasG, Cg, nullptr, nullptr, 256, 1024, 8);

    // ---- GRU scan v7 (writes F16 h-cols + At planes) ----
    k_gru7<<<256, 768, 0, stream>>>(Cg, (const uint4*)W4, gru_bhh, X_len, prof,
                                    F16, At_hi, At_lo);

    // ---- tran = [gruo|prof] @ tranH + b ----
    k_mgemm3<0, false, 1, 3, 0><<<128 * 2, 256, 0, stream>>>(At_hi, At_lo, THhi, THlo,
        tranH_b, nullptr, tran_hi, tran_lo, 320, 256, 2);

    // ---- slot logits = tran @ KM^T ----
    k_mgemm3<0, false, 0, 3, 0><<<128 * 1, 256, 0, stream>>>(tran_hi, tran_lo, KMhi, KMlo,
        nullptr, slotw, nullptr, nullptr, 256, 128, 1);

    // ---- fused softmax128 + VM scan + attn epilogue -> F16 cols 256..447 ----
    k_memf<<<B_, 256, 0, stream>>>(slotw, Cg, iniVam, prof, attnP_w, attnP_b, F16);

    // ---- logits(f16) = F @ out_w + out_b ----
    k_mgemm3<0, false, 2, 1, 1><<<128 * 16, 256, 0, stream>>>(
        (const bf16*)F16, nullptr, (const bf16*)OWf, nullptr,
        out_b, nullptr, (bf16*)LG16, nullptr, 448, 2000, 16);

    k_softmax2000<<<M_, 256, 0, stream>>>(LG16, out);
}

// Round 15
// 657.069 us; speedup vs baseline: 1.0557x; 1.0557x over previous
//
#include <hip/hip_runtime.h>
#include <hip/hip_bf16.h>
#include <cmath>

#define T_  64
#define B_  256
#define D_  2000
#define TN_ 3000
#define E_  256
#define H_  256
#define A_  128
#define V_  128
#define PS_ 64
#define PE_ 64
#define S_  128
#define G1N_ 1500
#define G1L_ 4
#define G2N_ 1500
#define G2L_ 6
#define M_  (T_ * B_)
#define KF_ (H_ + V_ + PE_)

typedef __attribute__((ext_vector_type(8))) short short8_t;
typedef __attribute__((ext_vector_type(4))) float floatx4;
typedef _Float16 __attribute__((ext_vector_type(2))) h2_t;
typedef _Float16 __attribute__((ext_vector_type(8))) h8_t;

static __device__ __forceinline__ float sigmoidf_(float x) {
    return 1.0f / (1.0f + __expf(-x));
}

static __device__ __forceinline__ void bsplit_(float v, __hip_bfloat16& hi, __hip_bfloat16& lo) {
    hi = __float2bfloat16(v);
    lo = __float2bfloat16(v - __bfloat162float(hi));
}

static __device__ __forceinline__ float dot2_(unsigned int w, unsigned int h, float acc) {
    union { unsigned int u; h2_t h; } cw, ch;
    cw.u = w; ch.u = h;
#if __has_builtin(__builtin_amdgcn_fdot2)
    return __builtin_amdgcn_fdot2(cw.h, ch.h, acc, false);
#else
    return acc + (float)cw.h[0] * (float)ch.h[0] + (float)cw.h[1] * (float)ch.h[1];
#endif
}

// async global->LDS, 16B per lane. LDS dst must be wave-uniform base + lane*16.
static __device__ __forceinline__ void gl_lds16(const void* g, void* l)
{
#if __has_builtin(__builtin_amdgcn_global_load_lds)
    __builtin_amdgcn_global_load_lds(
        (const __attribute__((address_space(1))) void*)g,
        (__attribute__((address_space(3))) void*)l, 16, 0, 0);
#else
    *(short8_t*)l = *(const short8_t*)g;
#endif
}

template<int DT>
static __device__ __forceinline__ floatx4 mfma16_(short8_t a, short8_t b, floatx4 c) {
    if constexpr (DT == 0) {
        return __builtin_amdgcn_mfma_f32_16x16x32_bf16(a, b, c, 0, 0, 0);
    } else {
        union { short8_t s; h8_t h; } ua, ub;
        ua.s = a; ub.s = b;
        return __builtin_amdgcn_mfma_f32_16x16x32_f16(ua.h, ub.h, c, 0, 0, 0);
    }
}

// ---------------------------------------------------------------------------
// Split MFMA GEMM, double-buffered global_load_lds staging + XCD remap.
// DT=0: bf16 planes (NPH=3 -> fp32-grade). DT=1: f16, NPH=1 (hi-only).
// B given as BT[Npad][K] row-major. M mult 128, K mult 32, Npad = nblk*128.
// EPI 1: sigmoid col<128 else tanh. EPI 2: sigmoid col<128, tanh col<256.
// OUTMODE 0: f32 Cf (ACCUM adds). 1: bf16 split (Chi,Clo). 2: f16 (Chi cast).
// ---------------------------------------------------------------------------
template<int EPI, bool ACCUM, int OUTMODE, int NPH, int DT>
__global__ __launch_bounds__(256)
void k_mgemm3(const __hip_bfloat16* __restrict__ Ahi, const __hip_bfloat16* __restrict__ Alo,
              const __hip_bfloat16* __restrict__ Bhi, const __hip_bfloat16* __restrict__ Blo,
              const float* __restrict__ bias, float* __restrict__ Cf,
              __hip_bfloat16* __restrict__ Chi, __hip_bfloat16* __restrict__ Clo,
              int K, int Nreal, int nblk)
{
    __shared__ __align__(16) short As[2][4096];
    __shared__ __align__(16) short Bs[2][4096];

    const int tid  = threadIdx.x;
    const int lane = tid & 63;
    const int w    = tid >> 6;
    const int wm   = w >> 1, wn = w & 1;
    const int lr   = lane & 15;
    const int lkc  = lane >> 4;

    const int bx = blockIdx.x;
    const int xcd = bx & 7, loc = bx >> 3;
    const int mchunk = (int)gridDim.x / (8 * nblk);
    const int m0 = (xcd * mchunk + loc / nblk) * 128;
    const int n0 = (loc % nblk) * 128;

    const int fa = 2 * w;
    const size_t aoff0 = (size_t)(m0 + fa * 16 + lr) * K + lkc * 8;
    const size_t aoff1 = aoff0 + (size_t)16 * K;
    const size_t boff0 = (size_t)(n0 + fa * 16 + lr) * K + lkc * 8;
    const size_t boff1 = boff0 + (size_t)16 * K;

    const int lA0 = (fa    ) * 512 + lane * 8;
    const int lA1 = (fa + 1) * 512 + lane * 8;

    floatx4 acc[4][4];
#pragma unroll
    for (int i = 0; i < 4; ++i)
#pragma unroll
        for (int j = 0; j < 4; ++j) acc[i][j] = floatx4{0.f, 0.f, 0.f, 0.f};

    const int KT = K >> 5;
    const int NT = NPH * KT;

    int s_ph = 0, s_k = 0;
    auto do_stage = [&](int buf) {
        const __hip_bfloat16* Ap = (s_ph == 2) ? Alo : Ahi;
        const __hip_bfloat16* Bp = (s_ph == 1) ? Blo : Bhi;
        gl_lds16(Ap + aoff0 + s_k, &As[buf][lA0]);
        gl_lds16(Ap + aoff1 + s_k, &As[buf][lA1]);
        gl_lds16(Bp + boff0 + s_k, &Bs[buf][lA0]);
        gl_lds16(Bp + boff1 + s_k, &Bs[buf][lA1]);
        s_k += 32;
        if (s_k >= K) { s_k = 0; ++s_ph; }
    };

    do_stage(0);
    __syncthreads();

#pragma unroll 1
    for (int t = 0; t < NT; ++t) {
        const int cur = t & 1;
        if (t + 1 < NT) do_stage(cur ^ 1);

        short8_t af[4], bf[4];
#pragma unroll
        for (int i = 0; i < 4; ++i)
            af[i] = *(const short8_t*)(const void*)&As[cur][(wm * 4 + i) * 512 + lane * 8];
#pragma unroll
        for (int j = 0; j < 4; ++j)
            bf[j] = *(const short8_t*)(const void*)&Bs[cur][(wn * 4 + j) * 512 + lane * 8];
#pragma unroll
        for (int i = 0; i < 4; ++i)
#pragma unroll
            for (int j = 0; j < 4; ++j)
                acc[i][j] = mfma16_<DT>(af[i], bf[j], acc[i][j]);

        __syncthreads();
    }

    // C/D layout (m89-verified): col=lane&15, row=(lane>>4)*4+r
#pragma unroll
    for (int i = 0; i < 4; ++i) {
        const int row = m0 + wm * 64 + i * 16 + (lane >> 4) * 4;
#pragma unroll
        for (int j = 0; j < 4; ++j) {
            const int col = n0 + wn * 64 + j * 16 + (lane & 15);
            if (col < Nreal) {
                float bv = bias ? bias[col] : 0.0f;
#pragma unroll
                for (int r = 0; r < 4; ++r) {
                    float v = acc[i][j][r] + bv;
                    if (EPI == 1) v = (col < 128) ? sigmoidf_(v) : tanhf(v);
                    if (EPI == 2) {
                        if (col < 128) v = sigmoidf_(v);
                        else if (col < 256) v = tanhf(v);
                    }
                    size_t o = (size_t)(row + r) * Nreal + col;
                    if (OUTMODE == 0) {
                        if (ACCUM) v += Cf[o];
                        Cf[o] = v;
                    } else if (OUTMODE == 1) {
                        __hip_bfloat16 h, l;
                        bsplit_(v, h, l);
                        Chi[o] = h; Clo[o] = l;
                    } else {
                        ((_Float16*)Chi)[o] = (_Float16)v;
                    }
                }
            }
        }
    }
}

// ---------------------------------------------------------------------------
// X f32 [16384][2000] -> XH f16 [16384][2048] (pad cols zero), vectorized
// ---------------------------------------------------------------------------
__global__ __launch_bounds__(256)
void k_cvtX(const float* __restrict__ X, _Float16* __restrict__ XH)
{
    int idx = blockIdx.x * blockDim.x + threadIdx.x;
    if (idx >= M_ * 256) return;
    int m = idx >> 8, d0 = (idx & 255) * 8;
    _Float16 h[8];
    if (d0 + 7 < D_) {
        float4 p = *(const float4*)(X + (size_t)m * D_ + d0);
        float4 q = *(const float4*)(X + (size_t)m * D_ + d0 + 4);
        h[0]=(_Float16)p.x; h[1]=(_Float16)p.y; h[2]=(_Float16)p.z; h[3]=(_Float16)p.w;
        h[4]=(_Float16)q.x; h[5]=(_Float16)q.y; h[6]=(_Float16)q.z; h[7]=(_Float16)q.w;
    } else {
#pragma unroll
        for (int i = 0; i < 8; ++i)
            h[i] = (d0 + i < D_) ? (_Float16)X[(size_t)m * D_ + d0 + i] : (_Float16)0.0f;
    }
    *(short8_t*)(XH + (size_t)m * 2048 + d0) = *(short8_t*)h;
}

// ---------------------------------------------------------------------------
// Xe GEMM: A = XH f16 [16384][2048], B = EMB f16 hi/lo planes [256][2048].
// Double-buffered DMA staging; XCD remap. Writes Xe bf16 split planes.
// ---------------------------------------------------------------------------
__global__ __launch_bounds__(256)
void k_mgemmXh(const _Float16* __restrict__ XH,
               const _Float16* __restrict__ Bhi, const _Float16* __restrict__ Blo,
               __hip_bfloat16* __restrict__ Chi, __hip_bfloat16* __restrict__ Clo)
{
    const int KP = 2048, NN = 256, nblk = 2;
    __shared__ __align__(16) short Ah[2][4096];
    __shared__ __align__(16) short Bh[2][4096];
    __shared__ __align__(16) short Bl[2][4096];

    const int tid  = threadIdx.x;
    const int lane = tid & 63;
    const int w    = tid >> 6;
    const int wm   = w >> 1, wn = w & 1;
    const int lr   = lane & 15;
    const int lkc  = lane >> 4;

    const int bx = blockIdx.x;
    const int xcd = bx & 7, loc = bx >> 3;
    const int mchunk = 256 / (8 * nblk);
    const int m0 = (xcd * mchunk + loc / nblk) * 128;
    const int n0 = (loc % nblk) * 128;

    const int fa = 2 * w;
    const size_t aoff0 = (size_t)(m0 + fa * 16 + lr) * KP + lkc * 8;
    const size_t aoff1 = aoff0 + (size_t)16 * KP;
    const size_t boff0 = (size_t)(n0 + fa * 16 + lr) * KP + lkc * 8;
    const size_t boff1 = boff0 + (size_t)16 * KP;

    const int lA0 = (fa    ) * 512 + lane * 8;
    const int lA1 = (fa + 1) * 512 + lane * 8;

    floatx4 acc[4][4];
#pragma unroll
    for (int i = 0; i < 4; ++i)
#pragma unroll
        for (int j = 0; j < 4; ++j) acc[i][j] = floatx4{0.f, 0.f, 0.f, 0.f};

    int s_k = 0;
    auto do_stage = [&](int buf) {
        gl_lds16(XH  + aoff0 + s_k, &Ah[buf][lA0]);
        gl_lds16(XH  + aoff1 + s_k, &Ah[buf][lA1]);
        gl_lds16(Bhi + boff0 + s_k, &Bh[buf][lA0]);
        gl_lds16(Bhi + boff1 + s_k, &Bh[buf][lA1]);
        gl_lds16(Blo + boff0 + s_k, &Bl[buf][lA0]);
        gl_lds16(Blo + boff1 + s_k, &Bl[buf][lA1]);
        s_k += 32;
    };

    do_stage(0);
    __syncthreads();

#pragma unroll 1
    for (int t = 0; t < KP / 32; ++t) {
        const int cur = t & 1;
        if (s_k < KP) do_stage(cur ^ 1);

        short8_t af[4], bfh[4], bfl[4];
#pragma unroll
        for (int i = 0; i < 4; ++i) {
            af[i]  = *(const short8_t*)(const void*)&Ah[cur][(wm * 4 + i) * 512 + lane * 8];
            bfh[i] = *(const short8_t*)(const void*)&Bh[cur][(wn * 4 + i) * 512 + lane * 8];
        }
#pragma unroll
        for (int i = 0; i < 4; ++i)
#pragma unroll
            for (int j = 0; j < 4; ++j)
                acc[i][j] = mfma16_<1>(af[i], bfh[j], acc[i][j]);
#pragma unroll
        for (int j = 0; j < 4; ++j)
            bfl[j] = *(const short8_t*)(const void*)&Bl[cur][(wn * 4 + j) * 512 + lane * 8];
#pragma unroll
        for (int i = 0; i < 4; ++i)
#pragma unroll
            for (int j = 0; j < 4; ++j)
                acc[i][j] = mfma16_<1>(af[i], bfl[j], acc[i][j]);

        __syncthreads();
    }

#pragma unroll
    for (int i = 0; i < 4; ++i) {
        const int row = m0 + wm * 64 + i * 16 + (lane >> 4) * 4;
#pragma unroll
        for (int j = 0; j < 4; ++j) {
            const int col = n0 + wn * 64 + j * 16 + (lane & 15);
#pragma unroll
            for (int r = 0; r < 4; ++r) {
                float v = acc[i][j][r];
                size_t o = (size_t)(row + r) * NN + col;
                __hip_bfloat16 h, l;
                bsplit_(v, h, l);
                Chi[o] = h; Clo[o] = l;
            }
        }
    }
}

// ---------------------------------------------------------------------------
// fp32 tiled GEMM (PP = ini_embd @ W2 only)
// ---------------------------------------------------------------------------
template<int BM, int BN, int BK, int TM, int TN>
__global__ __launch_bounds__(256)
void k_gemm(const float* __restrict__ A, const float* __restrict__ B,
            float* __restrict__ C, int M, int N, int K)
{
    __shared__ float As[BK][BM + 4];
    __shared__ float Bs[BK][BN + 4];
    const int tid = threadIdx.y * blockDim.x + threadIdx.x;
    const int m0 = blockIdx.y * BM;
    const int n0 = blockIdx.x * BN;
    float acc[TM][TN];
#pragma unroll
    for (int i = 0; i < TM; ++i)
#pragma unroll
        for (int j = 0; j < TN; ++j) acc[i][j] = 0.0f;
    for (int k0 = 0; k0 < K; k0 += BK) {
#pragma unroll
        for (int i = tid; i < BM * BK; i += 256) {
            int r = i / BK, c = i % BK;
            int m = m0 + r;
            As[c][r] = (m < M) ? A[(size_t)m * K + k0 + c] : 0.0f;
        }
#pragma unroll
        for (int i = tid; i < BK * BN; i += 256) {
            int r = i / BN, c = i % BN;
            Bs[r][c] = B[(size_t)(k0 + r) * N + n0 + c];
        }
        __syncthreads();
#pragma unroll
        for (int kk = 0; kk < BK; ++kk) {
            float a[TM], b[TN];
#pragma unroll
            for (int i = 0; i < TM; ++i) a[i] = As[kk][threadIdx.y * TM + i];
#pragma unroll
            for (int j = 0; j < TN; ++j) b[j] = Bs[kk][threadIdx.x * TN + j];
#pragma unroll
            for (int i = 0; i < TM; ++i)
#pragma unroll
                for (int j = 0; j < TN; ++j) acc[i][j] += a[i] * b[j];
        }
        __syncthreads();
    }
#pragma unroll
    for (int i = 0; i < TM; ++i) {
        int m = m0 + threadIdx.y * TM + i;
        if (m >= M) continue;
#pragma unroll
        for (int j = 0; j < TN; ++j)
            C[(size_t)m * N + n0 + threadIdx.x * TN + j] = acc[i][j];
    }
}

// ---------------------------------------------------------------------------
// Merged weight-pack kernel (segment-partitioned flat index).
// ---------------------------------------------------------------------------
__global__ __launch_bounds__(256)
void k_packall(const float* __restrict__ Wa_w,
               const float* __restrict__ erase_w, const float* __restrict__ add_w,
               const float* __restrict__ Wih,
               const float* __restrict__ erase_b, const float* __restrict__ add_b,
               const float* __restrict__ bih,
               const float* __restrict__ tranH_w, const float* __restrict__ out_w,
               const float* __restrict__ ini_embd, const int* __restrict__ KMIds,
               const float* __restrict__ Whh,
               float* __restrict__ W2p,
               __hip_bfloat16* __restrict__ WGhi, __hip_bfloat16* __restrict__ WGlo,
               float* __restrict__ biasG,
               __hip_bfloat16* __restrict__ THhi, __hip_bfloat16* __restrict__ THlo,
               _Float16* __restrict__ OWf,
               __hip_bfloat16* __restrict__ KMhi, __hip_bfloat16* __restrict__ KMlo,
               unsigned int* __restrict__ W4)
{
    int idx = blockIdx.x * blockDim.x + threadIdx.x;
    if (idx < 65536) {
        int e = idx >> 8, j = idx & 255;
        W2p[idx] = (j < A_) ? Wa_w[(size_t)e * A_ + j]
                            : Wa_w[(size_t)(E_ + e) * A_ + (j - A_)];
        return;
    }
    idx -= 65536;
    if (idx < 262144) {
        int n = idx >> 8, k = idx & 255;
        float v;
        if (n < 128)      v = erase_w[(size_t)k * V_ + n];
        else if (n < 256) v = add_w[(size_t)k * V_ + (n - 128)];
        else              v = Wih[(size_t)(n - 256) * 256 + k];
        bsplit_(v, WGhi[idx], WGlo[idx]);
        return;
    }
    idx -= 262144;
    if (idx < 1024) {
        biasG[idx] = (idx < 128) ? erase_b[idx]
                   : (idx < 256) ? add_b[idx - 128]
                                 : bih[idx - 256];
        return;
    }
    idx -= 1024;
    if (idx < 81920) {
        int n = idx / 320, k = idx % 320;
        bsplit_(tranH_w[(size_t)k * 256 + n], THhi[idx], THlo[idx]);
        return;
    }
    idx -= 81920;
    if (idx < 917504) {
        int n = idx / 448, k = idx % 448;
        OWf[idx] = (n < D_) ? (_Float16)out_w[(size_t)k * D_ + n] : (_Float16)0.0f;
        return;
    }
    idx -= 917504;
    if (idx < 32768) {
        int s = idx >> 8, k = idx & 255;
        bsplit_(ini_embd[(size_t)KMIds[s] * E_ + k], KMhi[idx], KMlo[idx]);
        return;
    }
    idx -= 32768;
    if (idx < 98304) {                                   // W4[32][768][4]
        int j = idx / 128, e2 = idx % 128;
        union { unsigned int u; h2_t h; } c;
        c.h[0] = (_Float16)Whh[(size_t)j * 256 + 2 * e2];
        c.h[1] = (_Float16)Whh[(size_t)j * 256 + 2 * e2 + 1];
        int ch = e2 >> 2, i = e2 & 3;
        W4[((size_t)ch * 768 + j) * 4 + i] = c.u;
    }
}

__global__ void k_prof(const float* __restrict__ profiles, const float* __restrict__ emP_w,
                       const float* __restrict__ emP_b, float* __restrict__ prof)
{
    int b = blockIdx.x, j = threadIdx.x;
    float acc = emP_b[j];
    for (int k = 0; k < PS_; ++k) acc += profiles[(size_t)b * PS_ + k] * emP_w[(size_t)k * PE_ + j];
    prof[(size_t)b * PE_ + j] = acc;
}

// embMT full: dst[e][d] = f16 split of embG[mapInfo[d]][e], d<2000 else 0
__global__ void k_embMT_f16(const float* __restrict__ embG, const int* __restrict__ mapInfo,
                            _Float16* __restrict__ hi, _Float16* __restrict__ lo)
{
    int idx = blockIdx.x * blockDim.x + threadIdx.x;
    if (idx >= 256 * 2048) return;
    int e = idx >> 11, d = idx & 2047;
    float v = (d < D_) ? embG[(size_t)mapInfo[d] * E_ + e] : 0.0f;
    _Float16 h = (_Float16)v;
    hi[idx] = h;
    lo[idx] = (_Float16)(v - (float)h);
}

// ---------------------------------------------------------------------------
// GRAM group attention
// ---------------------------------------------------------------------------
__global__ void k_group_embed(const float* __restrict__ PP, const float* __restrict__ Wa_b,
                              const float* __restrict__ Ua_w, const float* __restrict__ ini_embd,
                              const int* __restrict__ leaves1, const int* __restrict__ anc1,
                              const int* __restrict__ leaves2, const int* __restrict__ anc2,
                              float* __restrict__ embedG)
{
    int n = blockIdx.x;
    int lane = threadIdx.x;
    const int* lv; const int* ac; int L;
    if (n < G1N_) { L = G1L_; lv = leaves1 + (size_t)n * G1L_; ac = anc1 + (size_t)n * G1L_; }
    else { int n2 = n - G1N_; L = G2L_; lv = leaves2 + (size_t)n2 * G2L_; ac = anc2 + (size_t)n2 * G2L_; }

    float score[6]; int ai[6];
    for (int l = 0; l < L; ++l) {
        int li = lv[l]; int av = ac[l]; ai[l] = av;
        float s = 0.0f;
        for (int a = lane; a < A_; a += 64) {
            float hv = tanhf(PP[(size_t)li * 256 + a] + PP[(size_t)av * 256 + 128 + a] + Wa_b[a]);
            s += hv * Ua_w[a];
        }
        for (int o = 32; o; o >>= 1) s += __shfl_xor(s, o);
        score[l] = s;
    }
    float mx = -1e30f;
    for (int l = 0; l < L; ++l) mx = fmaxf(mx, score[l]);
    float w[6], sum = 0.0f;
    for (int l = 0; l < L; ++l) { w[l] = __expf(score[l] - mx); sum += w[l]; }
    float inv = 1.0f / sum;
    for (int e = lane; e < E_; e += 64) {
        float acc = 0.0f;
        for (int l = 0; l < L; ++l) acc += w[l] * inv * ini_embd[(size_t)ai[l] * E_ + e];
        embedG[(size_t)n * E_ + e] = acc;
    }
}

// ---------------------------------------------------------------------------
// GRU scan v7: 256 wgs x 768 threads, 1 sample/wg.
// Weights streamed as uint4 [32][768][4], explicit 8-deep double buffer.
// h written directly to F16 cols 0..255 and At planes; prof section of At
// written by threads 256..319.
// ---------------------------------------------------------------------------
__global__ __launch_bounds__(768)
void k_gru7(const float* __restrict__ Cg, const uint4* __restrict__ W4,
            const float* __restrict__ bhh, const int* __restrict__ X_len,
            const float* __restrict__ prof, _Float16* __restrict__ F,
            __hip_bfloat16* __restrict__ At_hi, __hip_bfloat16* __restrict__ At_lo)
{
    const int b = blockIdx.x;
    const int tid = threadIdx.x;

    __shared__ uint4 h2S[32];
    __shared__ float ghS[768];
    __shared__ float gxnS[256];

    if (tid < 128) ((unsigned int*)h2S)[tid] = 0u;

    float hreg = 0.0f;
    const int len = X_len[b];
    const float bj = bhh[tid];

    __hip_bfloat16 phi, plo;
    if (tid >= 256 && tid < 320)
        bsplit_(prof[(size_t)b * PE_ + (tid - 256)], phi, plo);

    __syncthreads();

#define DOT8(BUF, BASE)                                                     \
    {                                                                       \
        _Pragma("unroll")                                                   \
        for (int s = 0; s < 8; ++s) {                                       \
            uint4 h = h2S[(BASE) + s];                                      \
            a0 = dot2_(BUF[s].x, h.x, a0);                                  \
            a0 = dot2_(BUF[s].y, h.y, a0);                                  \
            a0 = dot2_(BUF[s].z, h.z, a0);                                  \
            a0 = dot2_(BUF[s].w, h.w, a0);                                  \
        }                                                                   \
    }
#define LOAD8(BUF, BASE)                                                    \
    {                                                                       \
        _Pragma("unroll")                                                   \
        for (int s = 0; s < 8; ++s)                                         \
            BUF[s] = W4[(size_t)((BASE) + s) * 768 + tid];                  \
    }

    for (int t = 0; t < T_; ++t) {
        float gxv = Cg[((size_t)t * B_ + b) * 1024 + 256 + tid];

        uint4 wa[8], wb[8];
        LOAD8(wa, 0)
        float a0 = bj;
        LOAD8(wb, 8)
        DOT8(wa, 0)
        LOAD8(wa, 16)
        DOT8(wb, 8)
        LOAD8(wb, 24)
        DOT8(wa, 16)
        DOT8(wb, 24)

        if (tid < 512) ghS[tid] = a0 + gxv;
        else { ghS[tid] = a0; gxnS[tid - 512] = gxv; }
        __syncthreads();

        if (tid < 256) {
            float r  = sigmoidf_(ghS[tid]);
            float z  = sigmoidf_(ghS[256 + tid]);
            float nn = tanhf(gxnS[tid] + r * ghS[512 + tid]);
            float hnew = (1.0f - z) * nn + z * hreg;
            bool msk = (t < len);
            hreg = msk ? hnew : hreg;
            float ov = msk ? hreg : 0.0f;
            size_t m = (size_t)t * B_ + b;
            F[m * KF_ + tid] = (_Float16)ov;
            size_t o = m * 320 + tid;
            bsplit_(ov, At_hi[o], At_lo[o]);
            float partner = __shfl_xor(hreg, 1);
            if (!(tid & 1)) {
                union { unsigned int u; h2_t h; } p;
                p.h[0] = (_Float16)hreg;
                p.h[1] = (_Float16)partner;
                ((unsigned int*)h2S)[tid >> 1] = p.u;
            }
        } else if (tid < 320) {
            size_t o = ((size_t)t * B_ + b) * 320 + tid;
            At_hi[o] = phi;
            At_lo[o] = plo;
        }
        __syncthreads();
    }
#undef DOT8
#undef LOAD8
}

// ---------------------------------------------------------------------------
// Slot softmax over 128 logits (proven round-12 form)
// ---------------------------------------------------------------------------
__global__ void k_softmax128(float* __restrict__ C)
{
    const int m = blockIdx.x;
    const size_t base = (size_t)m * S_;
    const int lane = threadIdx.x;
    float a = C[base + lane], b = C[base + 64 + lane];
    float mx = fmaxf(a, b);
    for (int o = 32; o; o >>= 1) mx = fmaxf(mx, __shfl_xor(mx, o));
    float e0 = __expf(a - mx), e1 = __expf(b - mx);
    float s = e0 + e1;
    for (int o = 32; o; o >>= 1) s += __shfl_xor(s, o);
    float inv = 1.0f / s;
    C[base + lane] = e0 * inv;
    C[base + 64 + lane] = e1 * inv;
}

// ---------------------------------------------------------------------------
// Value-memory scan — VM register-resident; era from fused Cg (stride 1024).
// Writes readv (f32, for k_attn) AND F16 cols 256..383.
// ---------------------------------------------------------------------------
__global__ __launch_bounds__(256)
void k_mem(const float* __restrict__ slotw, const float* __restrict__ Cg,
           const float* __restrict__ iniVam, float* __restrict__ readv,
           _Float16* __restrict__ F)
{
    const int b = blockIdx.x;
    const int tid = threadIdx.x;
    const int v = tid & (V_ - 1);
    const int sh = tid >> 7;
    const int sbase = sh * 64;

    float VM[64];
#pragma unroll
    for (int i = 0; i < 64; ++i) VM[i] = iniVam[(size_t)(sbase + i) * V_ + v];

    __shared__ float swL[S_];
    __shared__ float eaL[2 * V_];
    __shared__ float part[V_];

    for (int t = 0; t < T_; ++t) {
        size_t m = (size_t)t * B_ + b;
        if (tid < S_) swL[tid] = slotw[m * S_ + tid];
        eaL[tid] = Cg[m * 1024 + tid];
        __syncthreads();

        float er = eaL[v], ad = eaL[V_ + v];
        float p0 = 0.0f, p1 = 0.0f, p2 = 0.0f, p3 = 0.0f;
#pragma unroll
        for (int i = 0; i < 16; ++i) {
            float s0 = swL[sbase + 4 * i];
            float s1 = swL[sbase + 4 * i + 1];
            float s2 = swL[sbase + 4 * i + 2];
            float s3 = swL[sbase + 4 * i + 3];
            float v0 = VM[4 * i], v1 = VM[4 * i + 1], v2 = VM[4 * i + 2], v3 = VM[4 * i + 3];
            p0 += s0 * v0; p1 += s1 * v1; p2 += s2 * v2; p3 += s3 * v3;
            VM[4 * i]     = v0 * (1.0f - s0 * er) + s0 * ad;
            VM[4 * i + 1] = v1 * (1.0f - s1 * er) + s1 * ad;
            VM[4 * i + 2] = v2 * (1.0f - s2 * er) + s2 * ad;
            VM[4 * i + 3] = v3 * (1.0f - s3 * er) + s3 * ad;
        }
        float acc = (p0 + p1) + (p2 + p3);
        if (sh == 1) part[v] = acc;
        __syncthreads();
        if (sh == 0) {
            float rv = acc + part[v];
            readv[m * V_ + v] = rv;
            F[m * KF_ + H_ + v] = (_Float16)rv;
        }
        __syncthreads();
    }
}

// ---------------------------------------------------------------------------
// prof2 epilogue: F16 cols 384..447. grid = M_, block = 64.
// Same serial-k dot as the verified build_final.
// ---------------------------------------------------------------------------
__global__ __launch_bounds__(64)
void k_attn(const float* __restrict__ readv, const float* __restrict__ prof,
            const float* __restrict__ attnP_w, const float* __restrict__ attnP_b,
            _Float16* __restrict__ F)
{
    const int m = blockIdx.x;
    const int b = m & (B_ - 1);
    const int pe = threadIdx.x;
    __shared__ float rd[V_];
    __shared__ float pf[PE_];
    rd[pe] = readv[(size_t)m * V_ + pe];
    rd[64 + pe] = readv[(size_t)m * V_ + 64 + pe];
    pf[pe] = prof[(size_t)b * PE_ + pe];
    __syncthreads();

    float a = attnP_b[pe];
    for (int k = 0; k < PE_; ++k) a += pf[k] * attnP_w[(size_t)k * PE_ + pe];
    for (int k = 0; k < V_; ++k) a += rd[k] * attnP_w[(size_t)(PE_ + k) * PE_ + pe];
    a = fmaxf(a, 0.0f);
    F[(size_t)m * KF_ + H_ + V_ + pe] = (_Float16)(pf[pe] * a);
}

// reads f16 logits, writes f32 probabilities to d_out
__global__ __launch_bounds__(256)
void k_softmax2000(const _Float16* __restrict__ L, float* __restrict__ C)
{
    const int m = blockIdx.x;
    const size_t base = (size_t)m * D_;
    const int tid = threadIdx.x;
    const int wid = tid >> 6, lane = tid & 63;
    __shared__ float red[4], red2[4];

    float v[8];
#pragma unroll
    for (int i = 0; i < 8; ++i) {
        int d = i * 256 + tid;
        v[i] = (d < D_) ? (float)L[base + d] : -1e30f;
    }
    float mx = v[0];
#pragma unroll
    for (int i = 1; i < 8; ++i) mx = fmaxf(mx, v[i]);
    for (int o = 32; o; o >>= 1) mx = fmaxf(mx, __shfl_xor(mx, o));
    if (lane == 0) red[wid] = mx;
    __syncthreads();
    mx = fmaxf(fmaxf(red[0], red[1]), fmaxf(red[2], red[3]));

    float sum = 0.0f;
#pragma unroll
    for (int i = 0; i < 8; ++i) { v[i] = __expf(v[i] - mx); sum += v[i]; }
    for (int o = 32; o; o >>= 1) sum += __shfl_xor(sum, o);
    if (lane == 0) red2[wid] = sum;
    __syncthreads();
    sum = red2[0] + red2[1] + red2[2] + red2[3];
    float inv = 1.0f / sum;
#pragma unroll
    for (int i = 0; i < 8; ++i) {
        int d = i * 256 + tid;
        if (d < D_) C[base + d] = v[i] * inv;
    }
}

// ---------------------------------------------------------------------------
// Launch
// ---------------------------------------------------------------------------
extern "C" void kernel_launch(void* const* d_in, const int* in_sizes, int n_in,
                              void* d_out, int out_size, void* d_ws, size_t ws_size,
                              hipStream_t stream)
{
    const float* X        = (const float*)d_in[0];
    const float* profiles = (const float*)d_in[1];
    const float* ini_embd = (const float*)d_in[2];
    const float* Wa_w     = (const float*)d_in[3];
    const float* Wa_b     = (const float*)d_in[4];
    const float* Ua_w     = (const float*)d_in[5];
    const float* gru_Wih  = (const float*)d_in[6];
    const float* gru_Whh  = (const float*)d_in[7];
    const float* gru_bih  = (const float*)d_in[8];
    const float* gru_bhh  = (const float*)d_in[9];
    const float* tranH_w  = (const float*)d_in[10];
    const float* tranH_b  = (const float*)d_in[11];
    const float* out_w    = (const float*)d_in[12];
    const float* out_b    = (const float*)d_in[13];
    const float* erase_w  = (const float*)d_in[14];
    const float* erase_b  = (const float*)d_in[15];
    const float* add_w    = (const float*)d_in[16];
    const float* add_b    = (const float*)d_in[17];
    const float* iniVam   = (const float*)d_in[18];
    const float* emP_w    = (const float*)d_in[19];
    const float* emP_b    = (const float*)d_in[20];
    const float* attnP_w  = (const float*)d_in[21];
    const float* attnP_b  = (const float*)d_in[22];
    const int* KMIds   = (const int*)d_in[23];
    const int* leaves1 = (const int*)d_in[24];
    const int* anc1    = (const int*)d_in[25];
    const int* leaves2 = (const int*)d_in[26];
    const int* anc2    = (const int*)d_in[27];
    const int* mapInfo = (const int*)d_in[28];
    const int* X_len   = (const int*)d_in[29];

    char* ws = (char*)d_ws;
    float* out = (float*)d_out;
    typedef __hip_bfloat16 bf16;

    // ---- workspace layout (bytes) ----
    // R0 (67,108,864): early PP+embG; then XH f16; then Cg f32 (dead after
    //   k_mem); finally LG16 f16 logits (65.5 MB).
    // R1 (16,777,216): F16 [16384][448] f16.
    // R2 (16,777,216): Xe planes; later tran planes.
    // R3 (20,971,520): At planes; later slotw + readv.
    const size_t R0 = 0;
    const size_t R1 = 67108864;
    const size_t R2 = 83886080;
    const size_t R3 = 100663296;
    size_t P = 121634816;
    const size_t EMBHI = P; P += 1048576;
    const size_t EMBLO = P; P += 1048576;
    const size_t OWF  = P; P += 1835008;
    const size_t WGHI = P; P += 524288;
    const size_t WGLO = P; P += 524288;
    const size_t THHI = P; P += 163840;
    const size_t THLO = P; P += 163840;
    const size_t KMHI = P; P += 65536;
    const size_t KMLO = P; P += 65536;
    const size_t W4O  = P; P += 393216;   // Whh f16 uint4-pack [32][768][4]
    const size_t PROF = P; P += 65536;
    const size_t BIAS = P; P += 4096;
    const size_t W2O  = P; P += 262144;

    float* PP      = (float*)(ws + R0);
    float* embG    = (float*)(ws + R0 + 12288000);
    _Float16* XH   = (_Float16*)(ws + R0);
    float* Cg      = (float*)(ws + R0);
    _Float16* LG16 = (_Float16*)(ws + R0);
    _Float16* F16  = (_Float16*)(ws + R1);
    bf16*  Xe_hi   = (bf16*)(ws + R2);
    bf16*  Xe_lo   = (bf16*)(ws + R2 + 8388608);
    bf16*  tran_hi = (bf16*)(ws + R2);
    bf16*  tran_lo = (bf16*)(ws + R2 + 8388608);
    bf16*  At_hi   = (bf16*)(ws + R3);
    bf16*  At_lo   = (bf16*)(ws + R3 + 10485760);
    float* slotw   = (float*)(ws + R3);
    float* readv   = (float*)(ws + R3 + 10485760);
    _Float16* EMBhi = (_Float16*)(ws + EMBHI);
    _Float16* EMBlo = (_Float16*)(ws + EMBLO);
    _Float16* OWf = (_Float16*)(ws + OWF);
    bf16*  WGhi = (bf16*)(ws + WGHI); bf16* WGlo = (bf16*)(ws + WGLO);
    bf16*  THhi = (bf16*)(ws + THHI); bf16* THlo = (bf16*)(ws + THLO);
    bf16*  KMhi = (bf16*)(ws + KMHI); bf16* KMlo = (bf16*)(ws + KMLO);
    unsigned int* W4 = (unsigned int*)(ws + W4O);
    float* prof  = (float*)(ws + PROF);
    float* biasG = (float*)(ws + BIAS);
    float* W2p   = (float*)(ws + W2O);

    // ---- merged weight packs ----
    k_packall<<<5700, 256, 0, stream>>>(Wa_w, erase_w, add_w, gru_Wih,
        erase_b, add_b, gru_bih, tranH_w, out_w, ini_embd, KMIds, gru_Whh,
        W2p, WGhi, WGlo, biasG, THhi, THlo, OWf, KMhi, KMlo, W4);
    k_prof<<<B_, PE_, 0, stream>>>(profiles, emP_w, emP_b, prof);

    // ---- ontology attention -> embedMat f16 planes ----
    {
        dim3 blk(16, 16);
        dim3 grid(4, (TN_ + 63) / 64);
        k_gemm<64, 64, 16, 4, 4><<<grid, blk, 0, stream>>>(ini_embd, W2p, PP, TN_, 256, E_);
    }
    k_group_embed<<<G1N_ + G2N_, 64, 0, stream>>>(PP, Wa_b, Ua_w, ini_embd,
                                                  leaves1, anc1, leaves2, anc2, embG);
    k_embMT_f16<<<(256 * 2048) / 256, 256, 0, stream>>>(embG, mapInfo, EMBhi, EMBlo);

    // ---- X -> f16 (overwrites PP/embG region; both dead) ----
    k_cvtX<<<(M_ * 256) / 256, 256, 0, stream>>>(X, XH);

    // ---- Xe = XH @ embM (double-buffered DMA, f16 2-phase) ----
    k_mgemmXh<<<128 * 2, 256, 0, stream>>>(XH, EMBhi, EMBlo, Xe_hi, Xe_lo);

    // ---- Cg = [era | gx] fused GEMM (bf16 3-phase, fp32-grade) ----
    k_mgemm3<2, false, 0, 3, 0><<<128 * 8, 256, 0, stream>>>(Xe_hi, Xe_lo, WGhi, WGlo,
        biasG, Cg, nullptr, nullptr, 256, 1024, 8);

    // ---- GRU scan v7 (writes F16 h-cols + At planes) ----
    k_gru7<<<256, 768, 0, stream>>>(Cg, (const uint4*)W4, gru_bhh, X_len, prof,
                                    F16, At_hi, At_lo);

    // ---- tran = [gruo|prof] @ tranH + b ----
    k_mgemm3<0, false, 1, 3, 0><<<128 * 2, 256, 0, stream>>>(At_hi, At_lo, THhi, THlo,
        tranH_b, nullptr, tran_hi, tran_lo, 320, 256, 2);

    // ---- slot logits = tran @ KM^T ----
    k_mgemm3<0, false, 0, 3, 0><<<128 * 1, 256, 0, stream>>>(tran_hi, tran_lo, KMhi, KMlo,
        nullptr, slotw, nullptr, nullptr, 256, 128, 1);

    // ---- softmax over slots, VM scan (-> F cols 256..383), attn epilogue ----
    k_softmax128<<<M_, 64, 0, stream>>>(slotw);
    k_mem<<<B_, 256, 0, stream>>>(slotw, Cg, iniVam, readv, F16);
    k_attn<<<M_, 64, 0, stream>>>(readv, prof, attnP_w, attnP_b, F16);

    // ---- logits(f16) = F @ out_w + out_b ----
    k_mgemm3<0, false, 2, 1, 1><<<128 * 16, 256, 0, stream>>>(
        (const bf16*)F16, nullptr, (const bf16*)OWf, nullptr,
        out_b, nullptr, (bf16*)LG16, nullptr, 448, 2000, 16);

    k_softmax2000<<<M_, 256, 0, stream>>>(LG16, out);
}

// Round 16
// 656.851 us; speedup vs baseline: 1.0560x; 1.0003x over previous
//
#include <hip/hip_runtime.h>
#include <hip/hip_bf16.h>
#include <cmath>

#define T_  64
#define B_  256
#define D_  2000
#define TN_ 3000
#define E_  256
#define H_  256
#define A_  128
#define V_  128
#define PS_ 64
#define PE_ 64
#define S_  128
#define G1N_ 1500
#define G1L_ 4
#define G2N_ 1500
#define G2L_ 6
#define M_  (T_ * B_)
#define KF_ (H_ + V_ + PE_)

typedef __attribute__((ext_vector_type(8))) short short8_t;
typedef __attribute__((ext_vector_type(4))) float floatx4;
typedef _Float16 __attribute__((ext_vector_type(2))) h2_t;
typedef _Float16 __attribute__((ext_vector_type(8))) h8_t;

static __device__ __forceinline__ float sigmoidf_(float x) {
    return 1.0f / (1.0f + __expf(-x));
}

static __device__ __forceinline__ void bsplit_(float v, __hip_bfloat16& hi, __hip_bfloat16& lo) {
    hi = __float2bfloat16(v);
    lo = __float2bfloat16(v - __bfloat162float(hi));
}

static __device__ __forceinline__ float dot2_(unsigned int w, unsigned int h, float acc) {
    union { unsigned int u; h2_t h; } cw, ch;
    cw.u = w; ch.u = h;
#if __has_builtin(__builtin_amdgcn_fdot2)
    return __builtin_amdgcn_fdot2(cw.h, ch.h, acc, false);
#else
    return acc + (float)cw.h[0] * (float)ch.h[0] + (float)cw.h[1] * (float)ch.h[1];
#endif
}

// async global->LDS, 16B per lane. LDS dst must be wave-uniform base + lane*16.
static __device__ __forceinline__ void gl_lds16(const void* g, void* l)
{
#if __has_builtin(__builtin_amdgcn_global_load_lds)
    __builtin_amdgcn_global_load_lds(
        (const __attribute__((address_space(1))) void*)g,
        (__attribute__((address_space(3))) void*)l, 16, 0, 0);
#else
    *(short8_t*)l = *(const short8_t*)g;
#endif
}

template<int DT>
static __device__ __forceinline__ floatx4 mfma16_(short8_t a, short8_t b, floatx4 c) {
    if constexpr (DT == 0) {
        return __builtin_amdgcn_mfma_f32_16x16x32_bf16(a, b, c, 0, 0, 0);
    } else {
        union { short8_t s; h8_t h; } ua, ub;
        ua.s = a; ub.s = b;
        return __builtin_amdgcn_mfma_f32_16x16x32_f16(ua.h, ub.h, c, 0, 0, 0);
    }
}

// ---------------------------------------------------------------------------
// Split MFMA GEMM, double-buffered global_load_lds staging + XCD remap.
// DT=0: bf16 planes (NPH=3 -> fp32-grade). DT=1: f16, NPH=1 (hi-only).
// B given as BT[Npad][K] row-major. M mult 128, K mult 32, Npad = nblk*128.
// EPI 1: sigmoid col<128 else tanh. EPI 2: sigmoid col<128, tanh col<256.
// OUTMODE 0: f32 Cf (ACCUM adds). 1: bf16 split (Chi,Clo). 2: f16 (Chi cast).
// ---------------------------------------------------------------------------
template<int EPI, bool ACCUM, int OUTMODE, int NPH, int DT>
__global__ __launch_bounds__(256)
void k_mgemm3(const __hip_bfloat16* __restrict__ Ahi, const __hip_bfloat16* __restrict__ Alo,
              const __hip_bfloat16* __restrict__ Bhi, const __hip_bfloat16* __restrict__ Blo,
              const float* __restrict__ bias, float* __restrict__ Cf,
              __hip_bfloat16* __restrict__ Chi, __hip_bfloat16* __restrict__ Clo,
              int K, int Nreal, int nblk)
{
    __shared__ __align__(16) short As[2][4096];
    __shared__ __align__(16) short Bs[2][4096];

    const int tid  = threadIdx.x;
    const int lane = tid & 63;
    const int w    = tid >> 6;
    const int wm   = w >> 1, wn = w & 1;
    const int lr   = lane & 15;
    const int lkc  = lane >> 4;

    const int bx = blockIdx.x;
    const int xcd = bx & 7, loc = bx >> 3;
    const int mchunk = (int)gridDim.x / (8 * nblk);
    const int m0 = (xcd * mchunk + loc / nblk) * 128;
    const int n0 = (loc % nblk) * 128;

    const int fa = 2 * w;
    const size_t aoff0 = (size_t)(m0 + fa * 16 + lr) * K + lkc * 8;
    const size_t aoff1 = aoff0 + (size_t)16 * K;
    const size_t boff0 = (size_t)(n0 + fa * 16 + lr) * K + lkc * 8;
    const size_t boff1 = boff0 + (size_t)16 * K;

    const int lA0 = (fa    ) * 512 + lane * 8;
    const int lA1 = (fa + 1) * 512 + lane * 8;

    floatx4 acc[4][4];
#pragma unroll
    for (int i = 0; i < 4; ++i)
#pragma unroll
        for (int j = 0; j < 4; ++j) acc[i][j] = floatx4{0.f, 0.f, 0.f, 0.f};

    const int KT = K >> 5;
    const int NT = NPH * KT;

    int s_ph = 0, s_k = 0;
    auto do_stage = [&](int buf) {
        const __hip_bfloat16* Ap = (s_ph == 2) ? Alo : Ahi;
        const __hip_bfloat16* Bp = (s_ph == 1) ? Blo : Bhi;
        gl_lds16(Ap + aoff0 + s_k, &As[buf][lA0]);
        gl_lds16(Ap + aoff1 + s_k, &As[buf][lA1]);
        gl_lds16(Bp + boff0 + s_k, &Bs[buf][lA0]);
        gl_lds16(Bp + boff1 + s_k, &Bs[buf][lA1]);
        s_k += 32;
        if (s_k >= K) { s_k = 0; ++s_ph; }
    };

    do_stage(0);
    __syncthreads();

#pragma unroll 1
    for (int t = 0; t < NT; ++t) {
        const int cur = t & 1;
        if (t + 1 < NT) do_stage(cur ^ 1);

        short8_t af[4], bf[4];
#pragma unroll
        for (int i = 0; i < 4; ++i)
            af[i] = *(const short8_t*)(const void*)&As[cur][(wm * 4 + i) * 512 + lane * 8];
#pragma unroll
        for (int j = 0; j < 4; ++j)
            bf[j] = *(const short8_t*)(const void*)&Bs[cur][(wn * 4 + j) * 512 + lane * 8];
#pragma unroll
        for (int i = 0; i < 4; ++i)
#pragma unroll
            for (int j = 0; j < 4; ++j)
                acc[i][j] = mfma16_<DT>(af[i], bf[j], acc[i][j]);

        __syncthreads();
    }

    // C/D layout (m89-verified): col=lane&15, row=(lane>>4)*4+r
#pragma unroll
    for (int i = 0; i < 4; ++i) {
        const int row = m0 + wm * 64 + i * 16 + (lane >> 4) * 4;
#pragma unroll
        for (int j = 0; j < 4; ++j) {
            const int col = n0 + wn * 64 + j * 16 + (lane & 15);
            if (col < Nreal) {
                float bv = bias ? bias[col] : 0.0f;
#pragma unroll
                for (int r = 0; r < 4; ++r) {
                    float v = acc[i][j][r] + bv;
                    if (EPI == 1) v = (col < 128) ? sigmoidf_(v) : tanhf(v);
                    if (EPI == 2) {
                        if (col < 128) v = sigmoidf_(v);
                        else if (col < 256) v = tanhf(v);
                    }
                    size_t o = (size_t)(row + r) * Nreal + col;
                    if (OUTMODE == 0) {
                        if (ACCUM) v += Cf[o];
                        Cf[o] = v;
                    } else if (OUTMODE == 1) {
                        __hip_bfloat16 h, l;
                        bsplit_(v, h, l);
                        Chi[o] = h; Clo[o] = l;
                    } else {
                        ((_Float16*)Chi)[o] = (_Float16)v;
                    }
                }
            }
        }
    }
}

// ---------------------------------------------------------------------------
// X f32 [16384][2000] -> XH f16 [16384][2048] (pad cols zero), vectorized
// ---------------------------------------------------------------------------
__global__ __launch_bounds__(256)
void k_cvtX(const float* __restrict__ X, _Float16* __restrict__ XH)
{
    int idx = blockIdx.x * blockDim.x + threadIdx.x;
    if (idx >= M_ * 256) return;
    int m = idx >> 8, d0 = (idx & 255) * 8;
    _Float16 h[8];
    if (d0 + 7 < D_) {
        float4 p = *(const float4*)(X + (size_t)m * D_ + d0);
        float4 q = *(const float4*)(X + (size_t)m * D_ + d0 + 4);
        h[0]=(_Float16)p.x; h[1]=(_Float16)p.y; h[2]=(_Float16)p.z; h[3]=(_Float16)p.w;
        h[4]=(_Float16)q.x; h[5]=(_Float16)q.y; h[6]=(_Float16)q.z; h[7]=(_Float16)q.w;
    } else {
#pragma unroll
        for (int i = 0; i < 8; ++i)
            h[i] = (d0 + i < D_) ? (_Float16)X[(size_t)m * D_ + d0 + i] : (_Float16)0.0f;
    }
    *(short8_t*)(XH + (size_t)m * 2048 + d0) = *(short8_t*)h;
}

// ---------------------------------------------------------------------------
// Xe GEMM: A = XH f16 [16384][2048], B = EMB f16 hi/lo planes [256][2048].
// Double-buffered DMA staging; XCD remap. Writes Xe bf16 split planes.
// ---------------------------------------------------------------------------
__global__ __launch_bounds__(256)
void k_mgemmXh(const _Float16* __restrict__ XH,
               const _Float16* __restrict__ Bhi, const _Float16* __restrict__ Blo,
               __hip_bfloat16* __restrict__ Chi, __hip_bfloat16* __restrict__ Clo)
{
    const int KP = 2048, NN = 256, nblk = 2;
    __shared__ __align__(16) short Ah[2][4096];
    __shared__ __align__(16) short Bh[2][4096];
    __shared__ __align__(16) short Bl[2][4096];

    const int tid  = threadIdx.x;
    const int lane = tid & 63;
    const int w    = tid >> 6;
    const int wm   = w >> 1, wn = w & 1;
    const int lr   = lane & 15;
    const int lkc  = lane >> 4;

    const int bx = blockIdx.x;
    const int xcd = bx & 7, loc = bx >> 3;
    const int mchunk = 256 / (8 * nblk);
    const int m0 = (xcd * mchunk + loc / nblk) * 128;
    const int n0 = (loc % nblk) * 128;

    const int fa = 2 * w;
    const size_t aoff0 = (size_t)(m0 + fa * 16 + lr) * KP + lkc * 8;
    const size_t aoff1 = aoff0 + (size_t)16 * KP;
    const size_t boff0 = (size_t)(n0 + fa * 16 + lr) * KP + lkc * 8;
    const size_t boff1 = boff0 + (size_t)16 * KP;

    const int lA0 = (fa    ) * 512 + lane * 8;
    const int lA1 = (fa + 1) * 512 + lane * 8;

    floatx4 acc[4][4];
#pragma unroll
    for (int i = 0; i < 4; ++i)
#pragma unroll
        for (int j = 0; j < 4; ++j) acc[i][j] = floatx4{0.f, 0.f, 0.f, 0.f};

    int s_k = 0;
    auto do_stage = [&](int buf) {
        gl_lds16(XH  + aoff0 + s_k, &Ah[buf][lA0]);
        gl_lds16(XH  + aoff1 + s_k, &Ah[buf][lA1]);
        gl_lds16(Bhi + boff0 + s_k, &Bh[buf][lA0]);
        gl_lds16(Bhi + boff1 + s_k, &Bh[buf][lA1]);
        gl_lds16(Blo + boff0 + s_k, &Bl[buf][lA0]);
        gl_lds16(Blo + boff1 + s_k, &Bl[buf][lA1]);
        s_k += 32;
    };

    do_stage(0);
    __syncthreads();

#pragma unroll 1
    for (int t = 0; t < KP / 32; ++t) {
        const int cur = t & 1;
        if (s_k < KP) do_stage(cur ^ 1);

        short8_t af[4], bfh[4], bfl[4];
#pragma unroll
        for (int i = 0; i < 4; ++i) {
            af[i]  = *(const short8_t*)(const void*)&Ah[cur][(wm * 4 + i) * 512 + lane * 8];
            bfh[i] = *(const short8_t*)(const void*)&Bh[cur][(wn * 4 + i) * 512 + lane * 8];
        }
#pragma unroll
        for (int i = 0; i < 4; ++i)
#pragma unroll
            for (int j = 0; j < 4; ++j)
                acc[i][j] = mfma16_<1>(af[i], bfh[j], acc[i][j]);
#pragma unroll
        for (int j = 0; j < 4; ++j)
            bfl[j] = *(const short8_t*)(const void*)&Bl[cur][(wn * 4 + j) * 512 + lane * 8];
#pragma unroll
        for (int i = 0; i < 4; ++i)
#pragma unroll
            for (int j = 0; j < 4; ++j)
                acc[i][j] = mfma16_<1>(af[i], bfl[j], acc[i][j]);

        __syncthreads();
    }

#pragma unroll
    for (int i = 0; i < 4; ++i) {
        const int row = m0 + wm * 64 + i * 16 + (lane >> 4) * 4;
#pragma unroll
        for (int j = 0; j < 4; ++j) {
            const int col = n0 + wn * 64 + j * 16 + (lane & 15);
#pragma unroll
            for (int r = 0; r < 4; ++r) {
                float v = acc[i][j][r];
                size_t o = (size_t)(row + r) * NN + col;
                __hip_bfloat16 h, l;
                bsplit_(v, h, l);
                Chi[o] = h; Clo[o] = l;
            }
        }
    }
}

// ---------------------------------------------------------------------------
// fp32 tiled GEMM (PP = ini_embd @ W2 only)
// ---------------------------------------------------------------------------
template<int BM, int BN, int BK, int TM, int TN>
__global__ __launch_bounds__(256)
void k_gemm(const float* __restrict__ A, const float* __restrict__ B,
            float* __restrict__ C, int M, int N, int K)
{
    __shared__ float As[BK][BM + 4];
    __shared__ float Bs[BK][BN + 4];
    const int tid = threadIdx.y * blockDim.x + threadIdx.x;
    const int m0 = blockIdx.y * BM;
    const int n0 = blockIdx.x * BN;
    float acc[TM][TN];
#pragma unroll
    for (int i = 0; i < TM; ++i)
#pragma unroll
        for (int j = 0; j < TN; ++j) acc[i][j] = 0.0f;
    for (int k0 = 0; k0 < K; k0 += BK) {
#pragma unroll
        for (int i = tid; i < BM * BK; i += 256) {
            int r = i / BK, c = i % BK;
            int m = m0 + r;
            As[c][r] = (m < M) ? A[(size_t)m * K + k0 + c] : 0.0f;
        }
#pragma unroll
        for (int i = tid; i < BK * BN; i += 256) {
            int r = i / BN, c = i % BN;
            Bs[r][c] = B[(size_t)(k0 + r) * N + n0 + c];
        }
        __syncthreads();
#pragma unroll
        for (int kk = 0; kk < BK; ++kk) {
            float a[TM], b[TN];
#pragma unroll
            for (int i = 0; i < TM; ++i) a[i] = As[kk][threadIdx.y * TM + i];
#pragma unroll
            for (int j = 0; j < TN; ++j) b[j] = Bs[kk][threadIdx.x * TN + j];
#pragma unroll
            for (int i = 0; i < TM; ++i)
#pragma unroll
                for (int j = 0; j < TN; ++j) acc[i][j] += a[i] * b[j];
        }
        __syncthreads();
    }
#pragma unroll
    for (int i = 0; i < TM; ++i) {
        int m = m0 + threadIdx.y * TM + i;
        if (m >= M) continue;
#pragma unroll
        for (int j = 0; j < TN; ++j)
            C[(size_t)m * N + n0 + threadIdx.x * TN + j] = acc[i][j];
    }
}

// ---------------------------------------------------------------------------
// Merged weight-pack kernel (segment-partitioned flat index).
// ---------------------------------------------------------------------------
__global__ __launch_bounds__(256)
void k_packall(const float* __restrict__ Wa_w,
               const float* __restrict__ erase_w, const float* __restrict__ add_w,
               const float* __restrict__ Wih,
               const float* __restrict__ erase_b, const float* __restrict__ add_b,
               const float* __restrict__ bih,
               const float* __restrict__ tranH_w, const float* __restrict__ out_w,
               const float* __restrict__ ini_embd, const int* __restrict__ KMIds,
               const float* __restrict__ Whh,
               float* __restrict__ W2p,
               __hip_bfloat16* __restrict__ WGhi, __hip_bfloat16* __restrict__ WGlo,
               float* __restrict__ biasG,
               __hip_bfloat16* __restrict__ THhi, __hip_bfloat16* __restrict__ THlo,
               _Float16* __restrict__ OWf,
               __hip_bfloat16* __restrict__ KMhi, __hip_bfloat16* __restrict__ KMlo,
               unsigned int* __restrict__ W4)
{
    int idx = blockIdx.x * blockDim.x + threadIdx.x;
    if (idx < 65536) {
        int e = idx >> 8, j = idx & 255;
        W2p[idx] = (j < A_) ? Wa_w[(size_t)e * A_ + j]
                            : Wa_w[(size_t)(E_ + e) * A_ + (j - A_)];
        return;
    }
    idx -= 65536;
    if (idx < 262144) {
        int n = idx >> 8, k = idx & 255;
        float v;
        if (n < 128)      v = erase_w[(size_t)k * V_ + n];
        else if (n < 256) v = add_w[(size_t)k * V_ + (n - 128)];
        else              v = Wih[(size_t)(n - 256) * 256 + k];
        bsplit_(v, WGhi[idx], WGlo[idx]);
        return;
    }
    idx -= 262144;
    if (idx < 1024) {
        biasG[idx] = (idx < 128) ? erase_b[idx]
                   : (idx < 256) ? add_b[idx - 128]
                                 : bih[idx - 256];
        return;
    }
    idx -= 1024;
    if (idx < 81920) {
        int n = idx / 320, k = idx % 320;
        bsplit_(tranH_w[(size_t)k * 256 + n], THhi[idx], THlo[idx]);
        return;
    }
    idx -= 81920;
    if (idx < 917504) {
        int n = idx / 448, k = idx % 448;
        OWf[idx] = (n < D_) ? (_Float16)out_w[(size_t)k * D_ + n] : (_Float16)0.0f;
        return;
    }
    idx -= 917504;
    if (idx < 32768) {
        int s = idx >> 8, k = idx & 255;
        bsplit_(ini_embd[(size_t)KMIds[s] * E_ + k], KMhi[idx], KMlo[idx]);
        return;
    }
    idx -= 32768;
    if (idx < 98304) {                                   // W4[32][768][4]
        int j = idx / 128, e2 = idx % 128;
        union { unsigned int u; h2_t h; } c;
        c.h[0] = (_Float16)Whh[(size_t)j * 256 + 2 * e2];
        c.h[1] = (_Float16)Whh[(size_t)j * 256 + 2 * e2 + 1];
        int ch = e2 >> 2, i = e2 & 3;
        W4[((size_t)ch * 768 + j) * 4 + i] = c.u;
    }
}

__global__ void k_prof(const float* __restrict__ profiles, const float* __restrict__ emP_w,
                       const float* __restrict__ emP_b, float* __restrict__ prof)
{
    int b = blockIdx.x, j = threadIdx.x;
    float acc = emP_b[j];
    for (int k = 0; k < PS_; ++k) acc += profiles[(size_t)b * PS_ + k] * emP_w[(size_t)k * PE_ + j];
    prof[(size_t)b * PE_ + j] = acc;
}

// embMT full: dst[e][d] = f16 split of embG[mapInfo[d]][e], d<2000 else 0
__global__ void k_embMT_f16(const float* __restrict__ embG, const int* __restrict__ mapInfo,
                            _Float16* __restrict__ hi, _Float16* __restrict__ lo)
{
    int idx = blockIdx.x * blockDim.x + threadIdx.x;
    if (idx >= 256 * 2048) return;
    int e = idx >> 11, d = idx & 2047;
    float v = (d < D_) ? embG[(size_t)mapInfo[d] * E_ + e] : 0.0f;
    _Float16 h = (_Float16)v;
    hi[idx] = h;
    lo[idx] = (_Float16)(v - (float)h);
}

// ---------------------------------------------------------------------------
// GRAM group attention
// ---------------------------------------------------------------------------
__global__ void k_group_embed(const float* __restrict__ PP, const float* __restrict__ Wa_b,
                              const float* __restrict__ Ua_w, const float* __restrict__ ini_embd,
                              const int* __restrict__ leaves1, const int* __restrict__ anc1,
                              const int* __restrict__ leaves2, const int* __restrict__ anc2,
                              float* __restrict__ embedG)
{
    int n = blockIdx.x;
    int lane = threadIdx.x;
    const int* lv; const int* ac; int L;
    if (n < G1N_) { L = G1L_; lv = leaves1 + (size_t)n * G1L_; ac = anc1 + (size_t)n * G1L_; }
    else { int n2 = n - G1N_; L = G2L_; lv = leaves2 + (size_t)n2 * G2L_; ac = anc2 + (size_t)n2 * G2L_; }

    float score[6]; int ai[6];
    for (int l = 0; l < L; ++l) {
        int li = lv[l]; int av = ac[l]; ai[l] = av;
        float s = 0.0f;
        for (int a = lane; a < A_; a += 64) {
            float hv = tanhf(PP[(size_t)li * 256 + a] + PP[(size_t)av * 256 + 128 + a] + Wa_b[a]);
            s += hv * Ua_w[a];
        }
        for (int o = 32; o; o >>= 1) s += __shfl_xor(s, o);
        score[l] = s;
    }
    float mx = -1e30f;
    for (int l = 0; l < L; ++l) mx = fmaxf(mx, score[l]);
    float w[6], sum = 0.0f;
    for (int l = 0; l < L; ++l) { w[l] = __expf(score[l] - mx); sum += w[l]; }
    float inv = 1.0f / sum;
    for (int e = lane; e < E_; e += 64) {
        float acc = 0.0f;
        for (int l = 0; l < L; ++l) acc += w[l] * inv * ini_embd[(size_t)ai[l] * E_ + e];
        embedG[(size_t)n * E_ + e] = acc;
    }
}

// ---------------------------------------------------------------------------
// GRU scan v8: 256 wgs x 768 threads, 1 sample/wg.
// Weights streamed as uint4 [32][768][4], explicit 8-deep double buffer.
// FOUR interleaved accumulators (x/y/z/w lanes of each uint4 feed a0..a3)
// break the fdot2 dependency chain. h written directly to F16 cols 0..255
// and At planes; prof section of At written by threads 256..319.
// ---------------------------------------------------------------------------
__global__ __launch_bounds__(768)
void k_gru8(const float* __restrict__ Cg, const uint4* __restrict__ W4,
            const float* __restrict__ bhh, const int* __restrict__ X_len,
            const float* __restrict__ prof, _Float16* __restrict__ F,
            __hip_bfloat16* __restrict__ At_hi, __hip_bfloat16* __restrict__ At_lo)
{
    const int b = blockIdx.x;
    const int tid = threadIdx.x;

    __shared__ uint4 h2S[32];
    __shared__ float ghS[768];
    __shared__ float gxnS[256];

    if (tid < 128) ((unsigned int*)h2S)[tid] = 0u;

    float hreg = 0.0f;
    const int len = X_len[b];
    const float bj = bhh[tid];

    __hip_bfloat16 phi, plo;
    if (tid >= 256 && tid < 320)
        bsplit_(prof[(size_t)b * PE_ + (tid - 256)], phi, plo);

    __syncthreads();

#define DOT8(BUF, BASE)                                                     \
    {                                                                       \
        _Pragma("unroll")                                                   \
        for (int s = 0; s < 8; ++s) {                                       \
            uint4 h = h2S[(BASE) + s];                                      \
            a0 = dot2_(BUF[s].x, h.x, a0);                                  \
            a1 = dot2_(BUF[s].y, h.y, a1);                                  \
            a2 = dot2_(BUF[s].z, h.z, a2);                                  \
            a3 = dot2_(BUF[s].w, h.w, a3);                                  \
        }                                                                   \
    }
#define LOAD8(BUF, BASE)                                                    \
    {                                                                       \
        _Pragma("unroll")                                                   \
        for (int s = 0; s < 8; ++s)                                         \
            BUF[s] = W4[(size_t)((BASE) + s) * 768 + tid];                  \
    }

    for (int t = 0; t < T_; ++t) {
        float gxv = Cg[((size_t)t * B_ + b) * 1024 + 256 + tid];

        uint4 wa[8], wb[8];
        LOAD8(wa, 0)
        float a0 = 0.0f, a1 = 0.0f, a2 = 0.0f, a3 = 0.0f;
        LOAD8(wb, 8)
        DOT8(wa, 0)
        LOAD8(wa, 16)
        DOT8(wb, 8)
        LOAD8(wb, 24)
        DOT8(wa, 16)
        DOT8(wb, 24)
        float a = bj + ((a0 + a1) + (a2 + a3));

        if (tid < 512) ghS[tid] = a + gxv;
        else { ghS[tid] = a; gxnS[tid - 512] = gxv; }
        __syncthreads();

        if (tid < 256) {
            float r  = sigmoidf_(ghS[tid]);
            float z  = sigmoidf_(ghS[256 + tid]);
            float nn = tanhf(gxnS[tid] + r * ghS[512 + tid]);
            float hnew = (1.0f - z) * nn + z * hreg;
            bool msk = (t < len);
            hreg = msk ? hnew : hreg;
            float ov = msk ? hreg : 0.0f;
            size_t m = (size_t)t * B_ + b;
            F[m * KF_ + tid] = (_Float16)ov;
            size_t o = m * 320 + tid;
            bsplit_(ov, At_hi[o], At_lo[o]);
            float partner = __shfl_xor(hreg, 1);
            if (!(tid & 1)) {
                union { unsigned int u; h2_t h; } p;
                p.h[0] = (_Float16)hreg;
                p.h[1] = (_Float16)partner;
                ((unsigned int*)h2S)[tid >> 1] = p.u;
            }
        } else if (tid < 320) {
            size_t o = ((size_t)t * B_ + b) * 320 + tid;
            At_hi[o] = phi;
            At_lo[o] = plo;
        }
        __syncthreads();
    }
#undef DOT8
#undef LOAD8
}

// ---------------------------------------------------------------------------
// Slot softmax over 128 logits
// ---------------------------------------------------------------------------
__global__ void k_softmax128(float* __restrict__ C)
{
    const int m = blockIdx.x;
    const size_t base = (size_t)m * S_;
    const int lane = threadIdx.x;
    float a = C[base + lane], b = C[base + 64 + lane];
    float mx = fmaxf(a, b);
    for (int o = 32; o; o >>= 1) mx = fmaxf(mx, __shfl_xor(mx, o));
    float e0 = __expf(a - mx), e1 = __expf(b - mx);
    float s = e0 + e1;
    for (int o = 32; o; o >>= 1) s += __shfl_xor(s, o);
    float inv = 1.0f / s;
    C[base + lane] = e0 * inv;
    C[base + 64 + lane] = e1 * inv;
}

// ---------------------------------------------------------------------------
// Value-memory scan — VM register-resident; era from fused Cg (stride 1024).
// Writes readv (f32, for k_attn) AND F16 cols 256..383.
// ---------------------------------------------------------------------------
__global__ __launch_bounds__(256)
void k_mem(const float* __restrict__ slotw, const float* __restrict__ Cg,
           const float* __restrict__ iniVam, float* __restrict__ readv,
           _Float16* __restrict__ F)
{
    const int b = blockIdx.x;
    const int tid = threadIdx.x;
    const int v = tid & (V_ - 1);
    const int sh = tid >> 7;
    const int sbase = sh * 64;

    float VM[64];
#pragma unroll
    for (int i = 0; i < 64; ++i) VM[i] = iniVam[(size_t)(sbase + i) * V_ + v];

    __shared__ float swL[S_];
    __shared__ float eaL[2 * V_];
    __shared__ float part[V_];

    for (int t = 0; t < T_; ++t) {
        size_t m = (size_t)t * B_ + b;
        if (tid < S_) swL[tid] = slotw[m * S_ + tid];
        eaL[tid] = Cg[m * 1024 + tid];
        __syncthreads();

        float er = eaL[v], ad = eaL[V_ + v];
        float p0 = 0.0f, p1 = 0.0f, p2 = 0.0f, p3 = 0.0f;
#pragma unroll
        for (int i = 0; i < 16; ++i) {
            float s0 = swL[sbase + 4 * i];
            float s1 = swL[sbase + 4 * i + 1];
            float s2 = swL[sbase + 4 * i + 2];
            float s3 = swL[sbase + 4 * i + 3];
            float v0 = VM[4 * i], v1 = VM[4 * i + 1], v2 = VM[4 * i + 2], v3 = VM[4 * i + 3];
            p0 += s0 * v0; p1 += s1 * v1; p2 += s2 * v2; p3 += s3 * v3;
            VM[4 * i]     = v0 * (1.0f - s0 * er) + s0 * ad;
            VM[4 * i + 1] = v1 * (1.0f - s1 * er) + s1 * ad;
            VM[4 * i + 2] = v2 * (1.0f - s2 * er) + s2 * ad;
            VM[4 * i + 3] = v3 * (1.0f - s3 * er) + s3 * ad;
        }
        float acc = (p0 + p1) + (p2 + p3);
        if (sh == 1) part[v] = acc;
        __syncthreads();
        if (sh == 0) {
            float rv = acc + part[v];
            readv[m * V_ + v] = rv;
            F[m * KF_ + H_ + v] = (_Float16)rv;
        }
        __syncthreads();
    }
}

// ---------------------------------------------------------------------------
// prof2 epilogue: F16 cols 384..447. grid = M_, block = 64.
// ---------------------------------------------------------------------------
__global__ __launch_bounds__(64)
void k_attn(const float* __restrict__ readv, const float* __restrict__ prof,
            const float* __restrict__ attnP_w, const float* __restrict__ attnP_b,
            _Float16* __restrict__ F)
{
    const int m = blockIdx.x;
    const int b = m & (B_ - 1);
    const int pe = threadIdx.x;
    __shared__ float rd[V_];
    __shared__ float pf[PE_];
    rd[pe] = readv[(size_t)m * V_ + pe];
    rd[64 + pe] = readv[(size_t)m * V_ + 64 + pe];
    pf[pe] = prof[(size_t)b * PE_ + pe];
    __syncthreads();

    float a = attnP_b[pe];
    for (int k = 0; k < PE_; ++k) a += pf[k] * attnP_w[(size_t)k * PE_ + pe];
    for (int k = 0; k < V_; ++k) a += rd[k] * attnP_w[(size_t)(PE_ + k) * PE_ + pe];
    a = fmaxf(a, 0.0f);
    F[(size_t)m * KF_ + H_ + V_ + pe] = (_Float16)(pf[pe] * a);
}

// reads f16 logits, writes f32 probabilities to d_out
__global__ __launch_bounds__(256)
void k_softmax2000(const _Float16* __restrict__ L, float* __restrict__ C)
{
    const int m = blockIdx.x;
    const size_t base = (size_t)m * D_;
    const int tid = threadIdx.x;
    const int wid = tid >> 6, lane = tid & 63;
    __shared__ float red[4], red2[4];

    float v[8];
#pragma unroll
    for (int i = 0; i < 8; ++i) {
        int d = i * 256 + tid;
        v[i] = (d < D_) ? (float)L[base + d] : -1e30f;
    }
    float mx = v[0];
#pragma unroll
    for (int i = 1; i < 8; ++i) mx = fmaxf(mx, v[i]);
    for (int o = 32; o; o >>= 1) mx = fmaxf(mx, __shfl_xor(mx, o));
    if (lane == 0) red[wid] = mx;
    __syncthreads();
    mx = fmaxf(fmaxf(red[0], red[1]), fmaxf(red[2], red[3]));

    float sum = 0.0f;
#pragma unroll
    for (int i = 0; i < 8; ++i) { v[i] = __expf(v[i] - mx); sum += v[i]; }
    for (int o = 32; o; o >>= 1) sum += __shfl_xor(sum, o);
    if (lane == 0) red2[wid] = sum;
    __syncthreads();
    sum = red2[0] + red2[1] + red2[2] + red2[3];
    float inv = 1.0f / sum;
#pragma unroll
    for (int i = 0; i < 8; ++i) {
        int d = i * 256 + tid;
        if (d < D_) C[base + d] = v[i] * inv;
    }
}

// ---------------------------------------------------------------------------
// Launch
// ---------------------------------------------------------------------------
extern "C" void kernel_launch(void* const* d_in, const int* in_sizes, int n_in,
                              void* d_out, int out_size, void* d_ws, size_t ws_size,
                              hipStream_t stream)
{
    const float* X        = (const float*)d_in[0];
    const float* profiles = (const float*)d_in[1];
    const float* ini_embd = (const float*)d_in[2];
    const float* Wa_w     = (const float*)d_in[3];
    const float* Wa_b     = (const float*)d_in[4];
    const float* Ua_w     = (const float*)d_in[5];
    const float* gru_Wih  = (const float*)d_in[6];
    const float* gru_Whh  = (const float*)d_in[7];
    const float* gru_bih  = (const float*)d_in[8];
    const float* gru_bhh  = (const float*)d_in[9];
    const float* tranH_w  = (const float*)d_in[10];
    const float* tranH_b  = (const float*)d_in[11];
    const float* out_w    = (const float*)d_in[12];
    const float* out_b    = (const float*)d_in[13];
    const float* erase_w  = (const float*)d_in[14];
    const float* erase_b  = (const float*)d_in[15];
    const float* add_w    = (const float*)d_in[16];
    const float* add_b    = (const float*)d_in[17];
    const float* iniVam   = (const float*)d_in[18];
    const float* emP_w    = (const float*)d_in[19];
    const float* emP_b    = (const float*)d_in[20];
    const float* attnP_w  = (const float*)d_in[21];
    const float* attnP_b  = (const float*)d_in[22];
    const int* KMIds   = (const int*)d_in[23];
    const int* leaves1 = (const int*)d_in[24];
    const int* anc1    = (const int*)d_in[25];
    const int* leaves2 = (const int*)d_in[26];
    const int* anc2    = (const int*)d_in[27];
    const int* mapInfo = (const int*)d_in[28];
    const int* X_len   = (const int*)d_in[29];

    char* ws = (char*)d_ws;
    float* out = (float*)d_out;
    typedef __hip_bfloat16 bf16;

    // ---- workspace layout (bytes) ----
    const size_t R0 = 0;
    const size_t R1 = 67108864;
    const size_t R2 = 83886080;
    const size_t R3 = 100663296;
    size_t P = 121634816;
    const size_t EMBHI = P; P += 1048576;
    const size_t EMBLO = P; P += 1048576;
    const size_t OWF  = P; P += 1835008;
    const size_t WGHI = P; P += 524288;
    const size_t WGLO = P; P += 524288;
    const size_t THHI = P; P += 163840;
    const size_t THLO = P; P += 163840;
    const size_t KMHI = P; P += 65536;
    const size_t KMLO = P; P += 65536;
    const size_t W4O  = P; P += 393216;
    const size_t PROF = P; P += 65536;
    const size_t BIAS = P; P += 4096;
    const size_t W2O  = P; P += 262144;

    float* PP      = (float*)(ws + R0);
    float* embG    = (float*)(ws + R0 + 12288000);
    _Float16* XH   = (_Float16*)(ws + R0);
    float* Cg      = (float*)(ws + R0);
    _Float16* LG16 = (_Float16*)(ws + R0);
    _Float16* F16  = (_Float16*)(ws + R1);
    bf16*  Xe_hi   = (bf16*)(ws + R2);
    bf16*  Xe_lo   = (bf16*)(ws + R2 + 8388608);
    bf16*  tran_hi = (bf16*)(ws + R2);
    bf16*  tran_lo = (bf16*)(ws + R2 + 8388608);
    bf16*  At_hi   = (bf16*)(ws + R3);
    bf16*  At_lo   = (bf16*)(ws + R3 + 10485760);
    float* slotw   = (float*)(ws + R3);
    float* readv   = (float*)(ws + R3 + 10485760);
    _Float16* EMBhi = (_Float16*)(ws + EMBHI);
    _Float16* EMBlo = (_Float16*)(ws + EMBLO);
    _Float16* OWf = (_Float16*)(ws + OWF);
    bf16*  WGhi = (bf16*)(ws + WGHI); bf16* WGlo = (bf16*)(ws + WGLO);
    bf16*  THhi = (bf16*)(ws + THHI); bf16* THlo = (bf16*)(ws + THLO);
    bf16*  KMhi = (bf16*)(ws + KMHI); bf16* KMlo = (bf16*)(ws + KMLO);
    unsigned int* W4 = (unsigned int*)(ws + W4O);
    float* prof  = (float*)(ws + PROF);
    float* biasG = (float*)(ws + BIAS);
    float* W2p   = (float*)(ws + W2O);

    // ---- merged weight packs ----
    k_packall<<<5700, 256, 0, stream>>>(Wa_w, erase_w, add_w, gru_Wih,
        erase_b, add_b, gru_bih, tranH_w, out_w, ini_embd, KMIds, gru_Whh,
        W2p, WGhi, WGlo, biasG, THhi, THlo, OWf, KMhi, KMlo, W4);
    k_prof<<<B_, PE_, 0, stream>>>(profiles, emP_w, emP_b, prof);

    // ---- ontology attention -> embedMat f16 planes ----
    {
        dim3 blk(16, 16);
        dim3 grid(4, (TN_ + 63) / 64);
        k_gemm<64, 64, 16, 4, 4><<<grid, blk, 0, stream>>>(ini_embd, W2p, PP, TN_, 256, E_);
    }
    k_group_embed<<<G1N_ + G2N_, 64, 0, stream>>>(PP, Wa_b, Ua_w, ini_embd,
                                                  leaves1, anc1, leaves2, anc2, embG);
    k_embMT_f16<<<(256 * 2048) / 256, 256, 0, stream>>>(embG, mapInfo, EMBhi, EMBlo);

    // ---- X -> f16 (overwrites PP/embG region; both dead) ----
    k_cvtX<<<(M_ * 256) / 256, 256, 0, stream>>>(X, XH);

    // ---- Xe = XH @ embM (double-buffered DMA, f16 2-phase) ----
    k_mgemmXh<<<128 * 2, 256, 0, stream>>>(XH, EMBhi, EMBlo, Xe_hi, Xe_lo);

    // ---- Cg = [era | gx] fused GEMM (bf16 3-phase, fp32-grade) ----
    k_mgemm3<2, false, 0, 3, 0><<<128 * 8, 256, 0, stream>>>(Xe_hi, Xe_lo, WGhi, WGlo,
        biasG, Cg, nullptr, nullptr, 256, 1024, 8);

    // ---- GRU scan v8 (interleaved accumulators) ----
    k_gru8<<<256, 768, 0, stream>>>(Cg, (const uint4*)W4, gru_bhh, X_len, prof,
                                    F16, At_hi, At_lo);

    // ---- tran = [gruo|prof] @ tranH + b ----
    k_mgemm3<0, false, 1, 3, 0><<<128 * 2, 256, 0, stream>>>(At_hi, At_lo, THhi, THlo,
        tranH_b, nullptr, tran_hi, tran_lo, 320, 256, 2);

    // ---- slot logits = tran @ KM^T ----
    k_mgemm3<0, false, 0, 3, 0><<<128 * 1, 256, 0, stream>>>(tran_hi, tran_lo, KMhi, KMlo,
        nullptr, slotw, nullptr, nullptr, 256, 128, 1);

    // ---- softmax over slots, VM scan (-> F cols 256..383), attn epilogue ----
    k_softmax128<<<M_, 64, 0, stream>>>(slotw);
    k_mem<<<B_, 256, 0, stream>>>(slotw, Cg, iniVam, readv, F16);
    k_attn<<<M_, 64, 0, stream>>>(readv, prof, attnP_w, attnP_b, F16);

    // ---- logits(f16) = F @ out_w + out_b ----
    k_mgemm3<0, false, 2, 1, 1><<<128 * 16, 256, 0, stream>>>(
        (const bf16*)F16, nullptr, (const bf16*)OWf, nullptr,
        out_b, nullptr, (bf16*)LG16, nullptr, 448, 2000, 16);

    k_softmax2000<<<M_, 256, 0, stream>>>(LG16, out);
}